// Round 5
// baseline (6116.801 us; speedup 1.0000x reference)
//
#include <hip/hip_runtime.h>
#include <hip/hip_bf16.h>
#include <math.h>

#define B_   16
#define C_   16
#define S_   64
#define HW_  4096
#define T_   50
#define K_   26
#define F_   416   // C_*K_
#define HID_ 256
#define NC_  7
#define DT_  0.5f
#define BCHW_ (B_*C_*HW_)
#define M_   (B_*HW_)   // 65536 rows into the MLP

typedef short bf16x8 __attribute__((ext_vector_type(8)));
typedef float f32x4  __attribute__((ext_vector_type(4)));

__device__ __forceinline__ void gld_lds16(const void* g, void* l){
    __builtin_amdgcn_global_load_lds(
        (const __attribute__((address_space(1))) void*)g,
        (__attribute__((address_space(3))) void*)l, 16, 0, 0);
}

__device__ __forceinline__ float fast_tanh(float x){
    float ax = fabsf(x);
    float e  = __expf(2.f*ax);
    float r  = 1.f - 2.f/(e + 1.f);
    return copysignf(r, x);
}

// ---------------------------------------------------------------------------
// Fused multi-chain 3x3 conv, zero 'SAME' padding.
// Block = (slice of 16 rows, batch, chain); 1024 threads; each thread computes
// 1 output pixel for ALL 16 output channels.
// ---------------------------------------------------------------------------
template<int CIN, int ACT>
__global__ __launch_bounds__(1024) void convf_kernel(
    const float* __restrict__ in0, const float* __restrict__ in1, const float* __restrict__ in2,
    const float* __restrict__ w0,  const float* __restrict__ w1,  const float* __restrict__ w2,
    const float* __restrict__ b0,  const float* __restrict__ b1,  const float* __restrict__ b2,
    float* __restrict__ o0, float* __restrict__ o1, float* __restrict__ o2)
{
    __shared__ float slab[CIN][18][66];
    const int slice = blockIdx.x;
    const int b     = blockIdx.y;
    const int ch    = blockIdx.z;
    const float* in = (ch == 0) ? in0 : (ch == 1) ? in1 : in2;
    const float* w  = (ch == 0) ? w0  : (ch == 1) ? w1  : w2;
    const float* bb = (ch == 0) ? b0  : (ch == 1) ? b1  : b2;
    float* out      = (ch == 0) ? o0  : (ch == 1) ? o1  : o2;

    const int tid = threadIdx.x;
    const int y0  = slice * 16;

    for (int idx = tid; idx < CIN*18*66; idx += 1024){
        int ci  = idx / (18*66);
        int rem = idx % (18*66);
        int rr  = rem / 66;
        int cc  = rem % 66;
        int gy = y0 - 1 + rr;
        int gx = cc - 1;
        float v = 0.f;
        if ((unsigned)gy < 64u && (unsigned)gx < 64u)
            v = in[(size_t)(b*CIN + ci)*HW_ + gy*64 + gx];
        slab[ci][rr][cc] = v;
    }
    __syncthreads();

    const int x  = tid & 63;
    const int ry = tid >> 6;

    float acc[16];
    #pragma unroll
    for (int co = 0; co < 16; co++) acc[co] = bb[co];

    for (int ci = 0; ci < CIN; ci++){
        float p[3][3];
        #pragma unroll
        for (int dy = 0; dy < 3; dy++)
            #pragma unroll
            for (int dx = 0; dx < 3; dx++)
                p[dy][dx] = slab[ci][ry + dy][x + dx];
        #pragma unroll
        for (int co = 0; co < 16; co++){
            const float* wp = w + (size_t)(co*CIN + ci)*9;
            float s = acc[co];
            #pragma unroll
            for (int dy = 0; dy < 3; dy++)
                #pragma unroll
                for (int dx = 0; dx < 3; dx++)
                    s = fmaf(wp[dy*3 + dx], p[dy][dx], s);
            acc[co] = s;
        }
    }
    #pragma unroll
    for (int co = 0; co < 16; co++){
        float v = acc[co];
        v = ACT ? fast_tanh(v) : fmaxf(v, 0.f);
        out[(size_t)(b*16 + co)*HW_ + (y0 + ry)*64 + x] = v;
    }
}

// ---------------------------------------------------------------------------
// FUSED 50-step coRNN ODE + streaming Goertzel rfft-magnitude.
// One block per (b,c) field, 1024 threads, 4 pixels/thread (column segment).
// Field in LDS column-major stride 65 (conflict-free). Goertzel state for
// 4 pixels x 26 bins carried in registers, updated inline each step with
// fp32 ny (no yseq HBM round-trip). Epilogue writes bf16 magnitudes to
// f[(b*HW+hw)*416 + c*26 + k].
// ---------------------------------------------------------------------------
__global__ __launch_bounds__(1024) void ode_dft_kernel(
    const float* __restrict__ omega, const float* __restrict__ alpha,
    const float* __restrict__ hy0,   const float* __restrict__ wy,
    __hip_bfloat16* __restrict__ f)
{
    __shared__ float buf[2][64*65];
    const int blk = blockIdx.x;            // b*16 + c
    const int c   = blk & 15;
    const int b   = blk >> 4;
    const int tid = threadIdx.x;
    const int x   = tid & 63;
    const int sy  = (tid >> 6) << 2;       // 0,4,...,60
    const size_t off = (size_t)blk * HW_;

    float om[4], al[4], hz[4], hy[4];
    #pragma unroll
    for (int i = 0; i < 4; i++){
        size_t g = off + (size_t)(sy + i)*64 + x;
        om[i] = omega[g];
        al[i] = alpha[g];
        hz[i] = 0.f;
        hy[i] = hy0[g];
        buf[0][x*65 + sy + i] = hy[i];
    }
    float wv[9];
    const float* wp = wy + (size_t)(c*C_ + c)*9;
    #pragma unroll
    for (int j = 0; j < 9; j++) wv[j] = wp[j];

    float tcv[K_];
    #pragma unroll
    for (int k = 0; k < K_; k++)
        tcv[k] = 2.f * cosf(6.283185307179586f * (float)k / (float)T_);

    float g1[4*K_], g2[4*K_];
    #pragma unroll
    for (int i = 0; i < 4*K_; i++){ g1[i] = 0.f; g2[i] = 0.f; }
    __syncthreads();

    const int xl = ((x + 63) & 63) * 65;
    const int xr = ((x + 1)  & 63) * 65;
    const int xo = x * 65;
    const int ylo = (sy + 63) & 63;
    const int yhi = (sy + 4)  & 63;

    int cur = 0;
    for (int t = 0; t < T_; t++){
        const float* hp = buf[cur];
        float* hn = buf[cur ^ 1];
        float l[6], r[6];
        l[0] = hp[xl + ylo];  r[0] = hp[xr + ylo];
        #pragma unroll
        for (int i = 0; i < 4; i++){ l[i+1] = hp[xl + sy + i]; r[i+1] = hp[xr + sy + i]; }
        l[5] = hp[xl + yhi];  r[5] = hp[xr + yhi];
        float tN = hp[xo + ylo];
        float tS = hp[xo + yhi];

        float ny[4];
        #pragma unroll
        for (int i = 0; i < 4; i++){
            float up = (i == 0) ? tN : hy[i-1];
            float dn = (i == 3) ? tS : hy[i+1];
            float s = wv[0]*l[i]   + wv[1]*up    + wv[2]*r[i]
                    + wv[3]*l[i+1] + wv[4]*hy[i] + wv[5]*r[i+1]
                    + wv[6]*l[i+2] + wv[7]*dn    + wv[8]*r[i+2];
            float sf = fast_tanh(s);
            float nz = hz[i] + DT_*(sf - om[i]*hy[i] - al[i]*hz[i]);
            float v  = hy[i] + DT_*nz;
            hz[i] = nz;
            ny[i] = v;
        }
        #pragma unroll
        for (int i = 0; i < 4; i++){
            hy[i] = ny[i];
            hn[xo + sy + i] = ny[i];
        }
        // streaming Goertzel update: s0 = y + tc*s1 - s2
        #pragma unroll
        for (int i = 0; i < 4; i++){
            #pragma unroll
            for (int k = 0; k < K_; k++){
                float s0 = fmaf(tcv[k], g1[i*K_ + k], ny[i] - g2[i*K_ + k]);
                g2[i*K_ + k] = g1[i*K_ + k];
                g1[i*K_ + k] = s0;
            }
        }
        __syncthreads();
        cur ^= 1;
    }

    // magnitudes -> bf16, packed pair stores (52B contiguous per pixel)
    #pragma unroll
    for (int i = 0; i < 4; i++){
        const int row = b*HW_ + (sy + i)*64 + x;
        char* dst = (char*)(f + (size_t)row*F_ + c*K_);
        #pragma unroll
        for (int k2 = 0; k2 < K_/2; k2++){
            float m[2];
            #pragma unroll
            for (int e = 0; e < 2; e++){
                const int k = k2*2 + e;
                float s1 = g1[i*K_ + k], s2 = g2[i*K_ + k];
                float p = fmaf(s1, s1, fmaf(s2, s2, -tcv[k]*s1*s2));
                m[e] = sqrtf(fmaxf(p, 0.f));
            }
            __hip_bfloat16 b0 = __float2bfloat16(m[0]);
            __hip_bfloat16 b1 = __float2bfloat16(m[1]);
            unsigned int u = ((unsigned int)*(unsigned short*)&b1 << 16)
                           |  (unsigned int)*(unsigned short*)&b0;
            *(unsigned int*)(dst + 4*k2) = u;
        }
    }
}

// ---------------------------------------------------------------------------
// Weight prep: w[K][N] fp32 -> wt[N][K] bf16
// ---------------------------------------------------------------------------
__global__ __launch_bounds__(256) void prep_wt_kernel(
    const float* __restrict__ w, __hip_bfloat16* __restrict__ wt, int Kd, int N)
{
    const int n = blockIdx.x;
    for (int k = threadIdx.x; k < Kd; k += 256)
        wt[(size_t)n*Kd + k] = __float2bfloat16(w[(size_t)k*N + n]);
}

// ---------------------------------------------------------------------------
// MFMA GEMM: C = relu(A @ W + bias), bf16 in / fp32 acc / bf16 out.
// A [M][K] bf16, Wt [N][K] bf16, C [M][N] bf16. 128x128 tile, BK=32,
// 4 waves x (64x64), global_load_lds staging.
// ---------------------------------------------------------------------------
__global__ __launch_bounds__(256) void gemm_mfma_kernel(
    const __hip_bfloat16* __restrict__ A, const __hip_bfloat16* __restrict__ Wt,
    const float* __restrict__ bias, __hip_bfloat16* __restrict__ C,
    int M, int N, int Kd)
{
    __shared__ short As[128*32];
    __shared__ short Bs[128*32];
    const int tid  = threadIdx.x;
    const int lane = tid & 63;
    const int wave = tid >> 6;
    const int wm = (wave & 1) * 64;
    const int wn = (wave >> 1) * 64;
    const int m0 = blockIdx.x * 128;
    const int n0 = blockIdx.y * 128;

    f32x4 acc[4][4];
    #pragma unroll
    for (int i = 0; i < 4; i++)
        #pragma unroll
        for (int j = 0; j < 4; j++)
            acc[i][j] = (f32x4){0.f, 0.f, 0.f, 0.f};

    const int rloc = tid >> 2;
    const int kc   = (tid & 3) * 8;
    const char* Ag = (const char*)(A  + (size_t)(m0 + rloc)*Kd + kc);
    const char* Bg = (const char*)(Wt + (size_t)(n0 + rloc)*Kd + kc);
    const size_t rstride = (size_t)64 * Kd * 2;
    char* AsB = (char*)As + tid*16;
    char* BsB = (char*)Bs + tid*16;

    const int fa = (wm + (lane & 15)) * 32 + (lane >> 4) * 8;
    const int fb = (wn + (lane & 15)) * 32 + (lane >> 4) * 8;

    for (int k0 = 0; k0 < Kd; k0 += 32){
        const char* ag = Ag + (size_t)k0 * 2;
        const char* bg = Bg + (size_t)k0 * 2;
        gld_lds16(ag,           AsB);
        gld_lds16(ag + rstride, AsB + 4096);
        gld_lds16(bg,           BsB);
        gld_lds16(bg + rstride, BsB + 4096);
        __syncthreads();

        bf16x8 af[4], bfv[4];
        #pragma unroll
        for (int i = 0; i < 4; i++){
            af[i]  = *(const bf16x8*)&As[fa + i*16*32];
            bfv[i] = *(const bf16x8*)&Bs[fb + i*16*32];
        }
        #pragma unroll
        for (int i = 0; i < 4; i++)
            #pragma unroll
            for (int j = 0; j < 4; j++)
                acc[i][j] = __builtin_amdgcn_mfma_f32_16x16x32_bf16(
                                af[i], bfv[j], acc[i][j], 0, 0, 0);
        __syncthreads();
    }

    const int colb = n0 + wn + (lane & 15);
    const int rowb = m0 + wm + ((lane >> 4) << 2);
    #pragma unroll
    for (int j = 0; j < 4; j++){
        const int col = colb + j*16;
        const float bv = bias[col];
        #pragma unroll
        for (int i = 0; i < 4; i++){
            const int row0 = rowb + i*16;
            #pragma unroll
            for (int r = 0; r < 4; r++){
                float v = acc[i][j][r] + bv;
                v = fmaxf(v, 0.f);
                C[(size_t)(row0 + r)*N + col] = __float2bfloat16(v);
            }
        }
    }
}

// ---------------------------------------------------------------------------
// Final layer 256->7 (bf16 input) fused with (BHW,7)->(B,7,H,W) transpose.
// ---------------------------------------------------------------------------
__global__ __launch_bounds__(256) void final_kernel(
    const __hip_bfloat16* __restrict__ h, const float* __restrict__ w,
    const float* __restrict__ bias, float* __restrict__ out)
{
    __shared__ float wsm[HID_*NC_];
    __shared__ float bs[NC_];
    const int tid = threadIdx.x;
    for (int i = tid; i < HID_*NC_; i += 256) wsm[i] = w[i];
    if (tid < NC_) bs[tid] = bias[tid];
    __syncthreads();

    const int row = blockIdx.x*256 + tid;
    const uint4* hp = (const uint4*)(h + (size_t)row*HID_);
    float acc[NC_];
    #pragma unroll
    for (int j = 0; j < NC_; j++) acc[j] = bs[j];

    for (int k8 = 0; k8 < HID_/8; k8++){
        uint4 u = hp[k8];
        float v[8];
        v[0] = __uint_as_float(u.x << 16); v[1] = __uint_as_float(u.x & 0xffff0000u);
        v[2] = __uint_as_float(u.y << 16); v[3] = __uint_as_float(u.y & 0xffff0000u);
        v[4] = __uint_as_float(u.z << 16); v[5] = __uint_as_float(u.z & 0xffff0000u);
        v[6] = __uint_as_float(u.w << 16); v[7] = __uint_as_float(u.w & 0xffff0000u);
        const int k = k8*8;
        #pragma unroll
        for (int e = 0; e < 8; e++){
            #pragma unroll
            for (int j = 0; j < NC_; j++)
                acc[j] = fmaf(v[e], wsm[(k+e)*NC_ + j], acc[j]);
        }
    }
    const int b = row >> 12, hw = row & 4095;
    #pragma unroll
    for (int j = 0; j < NC_; j++)
        out[(size_t)(b*NC_ + j)*HW_ + hw] = acc[j];
}

// ---------------------------------------------------------------------------
// Workspace plan (peak 155,664,384 B; previous 159,383,552 proven OK):
//   fbuf bf16 [65536][416] @ 0                (54,525,952)  ODE+DFT w, GEMM1 r
//   conv temps 10 x 4 MiB  @ 54,525,952       (dead after ode_dft)
//   h1 bf16 @ 54,525,952   (33,554,432)  GEMM1 out (temps dead)
//   h2 bf16 @ 88,080,384   (33,554,432)
//   h3 bf16 @ 121,634,816  (33,554,432)
//   wt1/2/3 @ 155,189,248  (475,136)
// ---------------------------------------------------------------------------
extern "C" void kernel_launch(void* const* d_in, const int* in_sizes, int n_in,
                              void* d_out, int out_size, void* d_ws, size_t ws_size,
                              hipStream_t stream)
{
    const float* x     = (const float*)d_in[0];
    const float* om_w1 = (const float*)d_in[1];  const float* om_b1 = (const float*)d_in[2];
    const float* om_w2 = (const float*)d_in[3];  const float* om_b2 = (const float*)d_in[4];
    const float* om_w3 = (const float*)d_in[5];  const float* om_b3 = (const float*)d_in[6];
    const float* al_w1 = (const float*)d_in[7];  const float* al_b1 = (const float*)d_in[8];
    const float* al_w2 = (const float*)d_in[9];  const float* al_b2 = (const float*)d_in[10];
    const float* al_w3 = (const float*)d_in[11]; const float* al_b3 = (const float*)d_in[12];
    const float* hy_w1 = (const float*)d_in[13]; const float* hy_b1 = (const float*)d_in[14];
    const float* hy_w2 = (const float*)d_in[15]; const float* hy_b2 = (const float*)d_in[16];
    const float* hy_w3 = (const float*)d_in[17]; const float* hy_b3 = (const float*)d_in[18];
    const float* hy_w4 = (const float*)d_in[19]; const float* hy_b4 = (const float*)d_in[20];
    const float* wy    = (const float*)d_in[21];
    const float* ro_w1 = (const float*)d_in[22]; const float* ro_b1 = (const float*)d_in[23];
    const float* ro_w2 = (const float*)d_in[24]; const float* ro_b2 = (const float*)d_in[25];
    const float* ro_w3 = (const float*)d_in[26]; const float* ro_b3 = (const float*)d_in[27];
    const float* ro_w4 = (const float*)d_in[28]; const float* ro_b4 = (const float*)d_in[29];
    float* out = (float*)d_out;

    char* wsb = (char*)d_ws;
    __hip_bfloat16* fbuf = (__hip_bfloat16*)wsb;
    const size_t FB = (size_t)M_ * F_ * 2;                     // 54,525,952

    const size_t MB4 = (size_t)BCHW_ * 4;                      // 4 MiB
    float* om_t1 = (float*)(wsb + FB + 0*MB4);
    float* al_t1 = (float*)(wsb + FB + 1*MB4);
    float* hy_t1 = (float*)(wsb + FB + 2*MB4);
    float* om_t2 = (float*)(wsb + FB + 3*MB4);
    float* al_t2 = (float*)(wsb + FB + 4*MB4);
    float* hy_t2 = (float*)(wsb + FB + 5*MB4);
    float* omega = (float*)(wsb + FB + 6*MB4);
    float* alpha = (float*)(wsb + FB + 7*MB4);
    float* hy_t3 = (float*)(wsb + FB + 8*MB4);
    float* hy0   = (float*)(wsb + FB + 9*MB4);

    const size_t HB = (size_t)M_ * HID_ * 2;                   // 33,554,432
    __hip_bfloat16* h1 = (__hip_bfloat16*)(wsb + FB);
    __hip_bfloat16* h2 = (__hip_bfloat16*)(wsb + FB + HB);
    __hip_bfloat16* h3 = (__hip_bfloat16*)(wsb + FB + 2*HB);
    __hip_bfloat16* wt1 = (__hip_bfloat16*)(wsb + FB + 3*HB);
    __hip_bfloat16* wt2 = (__hip_bfloat16*)(wsb + FB + 3*HB + 212992);
    __hip_bfloat16* wt3 = (__hip_bfloat16*)(wsb + FB + 3*HB + 344064);

    // encoders: 3 chains fused per layer
    convf_kernel<1,0><<<dim3(4,B_,3), 1024, 0, stream>>>(
        x, x, x, om_w1, al_w1, hy_w1, om_b1, al_b1, hy_b1, om_t1, al_t1, hy_t1);
    convf_kernel<16,0><<<dim3(4,B_,3), 1024, 0, stream>>>(
        om_t1, al_t1, hy_t1, om_w2, al_w2, hy_w2, om_b2, al_b2, hy_b2, om_t2, al_t2, hy_t2);
    convf_kernel<16,0><<<dim3(4,B_,3), 1024, 0, stream>>>(
        om_t2, al_t2, hy_t2, om_w3, al_w3, hy_w3, om_b3, al_b3, hy_b3, omega, alpha, hy_t3);
    convf_kernel<16,1><<<dim3(4,B_,1), 1024, 0, stream>>>(
        hy_t3, hy_t3, hy_t3, hy_w4, hy_w4, hy_w4, hy_b4, hy_b4, hy_b4, hy0, hy0, hy0);
    // fused 50-step ODE + Goertzel rfft magnitude
    ode_dft_kernel<<<256, 1024, 0, stream>>>(omega, alpha, hy0, wy, fbuf);
    // weight transposes
    prep_wt_kernel<<<256, 256, 0, stream>>>(ro_w1, wt1, F_,   HID_);
    prep_wt_kernel<<<256, 256, 0, stream>>>(ro_w2, wt2, HID_, HID_);
    prep_wt_kernel<<<256, 256, 0, stream>>>(ro_w3, wt3, HID_, HID_);
    // readout MLP (MFMA)
    gemm_mfma_kernel<<<dim3(512,2), 256, 0, stream>>>(fbuf, wt1, ro_b1, h1, M_, HID_, F_);
    gemm_mfma_kernel<<<dim3(512,2), 256, 0, stream>>>(h1,   wt2, ro_b2, h2, M_, HID_, HID_);
    gemm_mfma_kernel<<<dim3(512,2), 256, 0, stream>>>(h2,   wt3, ro_b3, h3, M_, HID_, HID_);
    final_kernel<<<256, 256, 0, stream>>>(h3, ro_w4, ro_b4, out);
}

// Round 6
// 437.463 us; speedup vs baseline: 13.9824x; 13.9824x over previous
//
#include <hip/hip_runtime.h>
#include <hip/hip_bf16.h>
#include <hip/hip_fp16.h>
#include <math.h>

#define B_   16
#define C_   16
#define S_   64
#define HW_  4096
#define T_   50
#define K_   26
#define F_   416   // C_*K_
#define HID_ 256
#define NC_  7
#define DT_  0.5f
#define BCHW_ (B_*C_*HW_)
#define M_   (B_*HW_)   // 65536 rows into the MLP

typedef short    bf16x8 __attribute__((ext_vector_type(8)));
typedef _Float16 f16x8  __attribute__((ext_vector_type(8)));
typedef float    f32x4  __attribute__((ext_vector_type(4)));

__device__ __forceinline__ void gld_lds16(const void* g, void* l){
    __builtin_amdgcn_global_load_lds(
        (const __attribute__((address_space(1))) void*)g,
        (__attribute__((address_space(3))) void*)l, 16, 0, 0);
}

__device__ __forceinline__ float fast_tanh(float x){
    float ax = fabsf(x);
    float e  = __expf(2.f*ax);
    float r  = 1.f - 2.f/(e + 1.f);
    return copysignf(r, x);
}

// ---------------------------------------------------------------------------
// Fused multi-chain 3x3 conv, zero 'SAME' padding. (unchanged from round 4)
// ---------------------------------------------------------------------------
template<int CIN, int ACT>
__global__ __launch_bounds__(1024) void convf_kernel(
    const float* __restrict__ in0, const float* __restrict__ in1, const float* __restrict__ in2,
    const float* __restrict__ w0,  const float* __restrict__ w1,  const float* __restrict__ w2,
    const float* __restrict__ b0,  const float* __restrict__ b1,  const float* __restrict__ b2,
    float* __restrict__ o0, float* __restrict__ o1, float* __restrict__ o2)
{
    __shared__ float slab[CIN][18][66];
    const int slice = blockIdx.x;
    const int b     = blockIdx.y;
    const int ch    = blockIdx.z;
    const float* in = (ch == 0) ? in0 : (ch == 1) ? in1 : in2;
    const float* w  = (ch == 0) ? w0  : (ch == 1) ? w1  : w2;
    const float* bb = (ch == 0) ? b0  : (ch == 1) ? b1  : b2;
    float* out      = (ch == 0) ? o0  : (ch == 1) ? o1  : o2;

    const int tid = threadIdx.x;
    const int y0  = slice * 16;

    for (int idx = tid; idx < CIN*18*66; idx += 1024){
        int ci  = idx / (18*66);
        int rem = idx % (18*66);
        int rr  = rem / 66;
        int cc  = rem % 66;
        int gy = y0 - 1 + rr;
        int gx = cc - 1;
        float v = 0.f;
        if ((unsigned)gy < 64u && (unsigned)gx < 64u)
            v = in[(size_t)(b*CIN + ci)*HW_ + gy*64 + gx];
        slab[ci][rr][cc] = v;
    }
    __syncthreads();

    const int x  = tid & 63;
    const int ry = tid >> 6;

    float acc[16];
    #pragma unroll
    for (int co = 0; co < 16; co++) acc[co] = bb[co];

    for (int ci = 0; ci < CIN; ci++){
        float p[3][3];
        #pragma unroll
        for (int dy = 0; dy < 3; dy++)
            #pragma unroll
            for (int dx = 0; dx < 3; dx++)
                p[dy][dx] = slab[ci][ry + dy][x + dx];
        #pragma unroll
        for (int co = 0; co < 16; co++){
            const float* wp = w + (size_t)(co*CIN + ci)*9;
            float s = acc[co];
            #pragma unroll
            for (int dy = 0; dy < 3; dy++)
                #pragma unroll
                for (int dx = 0; dx < 3; dx++)
                    s = fmaf(wp[dy*3 + dx], p[dy][dx], s);
            acc[co] = s;
        }
    }
    #pragma unroll
    for (int co = 0; co < 16; co++){
        float v = acc[co];
        v = ACT ? fast_tanh(v) : fmaxf(v, 0.f);
        out[(size_t)(b*16 + co)*HW_ + (y0 + ry)*64 + x] = v;
    }
}

// ---------------------------------------------------------------------------
// 50-step coRNN ODE (round-4 version; output yseq now fp16 [t][bc][hw]).
// ---------------------------------------------------------------------------
__global__ __launch_bounds__(1024) void ode_kernel(
    const float* __restrict__ omega, const float* __restrict__ alpha,
    const float* __restrict__ hy0,   const float* __restrict__ wy,
    __half* __restrict__ yseq)
{
    __shared__ float buf[2][64*65];
    const int blk = blockIdx.x;            // b*16 + c
    const int c   = blk & 15;
    const int tid = threadIdx.x;
    const int x   = tid & 63;
    const int sy  = (tid >> 6) << 2;       // 0,4,...,60
    const size_t off = (size_t)blk * HW_;

    float om[4], al[4], hz[4], hy[4];
    #pragma unroll
    for (int i = 0; i < 4; i++){
        size_t g = off + (size_t)(sy + i)*64 + x;
        om[i] = omega[g];
        al[i] = alpha[g];
        hz[i] = 0.f;
        hy[i] = hy0[g];
        buf[0][x*65 + sy + i] = hy[i];
    }
    float wv[9];
    const float* wp = wy + (size_t)(c*C_ + c)*9;
    #pragma unroll
    for (int j = 0; j < 9; j++) wv[j] = wp[j];
    __syncthreads();

    const int xl = ((x + 63) & 63) * 65;
    const int xr = ((x + 1)  & 63) * 65;
    const int xo = x * 65;
    const int ylo = (sy + 63) & 63;
    const int yhi = (sy + 4)  & 63;

    int cur = 0;
    for (int t = 0; t < T_; t++){
        const float* hp = buf[cur];
        float* hn = buf[cur ^ 1];
        float l[6], r[6];
        l[0] = hp[xl + ylo];  r[0] = hp[xr + ylo];
        #pragma unroll
        for (int i = 0; i < 4; i++){ l[i+1] = hp[xl + sy + i]; r[i+1] = hp[xr + sy + i]; }
        l[5] = hp[xl + yhi];  r[5] = hp[xr + yhi];
        float tN = hp[xo + ylo];
        float tS = hp[xo + yhi];

        __half* yout = yseq + (size_t)t*BCHW_ + off;
        float ny[4];
        #pragma unroll
        for (int i = 0; i < 4; i++){
            float up = (i == 0) ? tN : hy[i-1];
            float dn = (i == 3) ? tS : hy[i+1];
            float s = wv[0]*l[i]   + wv[1]*up    + wv[2]*r[i]
                    + wv[3]*l[i+1] + wv[4]*hy[i] + wv[5]*r[i+1]
                    + wv[6]*l[i+2] + wv[7]*dn    + wv[8]*r[i+2];
            float sf = fast_tanh(s);
            float nz = hz[i] + DT_*(sf - om[i]*hy[i] - al[i]*hz[i]);
            float v  = hy[i] + DT_*nz;
            hz[i] = nz;
            ny[i] = v;
        }
        #pragma unroll
        for (int i = 0; i < 4; i++){
            hy[i] = ny[i];
            hn[xo + sy + i] = ny[i];
            yout[(sy + i)*64 + x] = __float2half(ny[i]);
        }
        __syncthreads();
        cur ^= 1;
    }
}

// ---------------------------------------------------------------------------
// MFMA DFT: D[bin][pix] = sum_t G[bin][t] * Y[pix][t], then magnitude.
// Basis rows interleaved: row 2k = cos(2*pi*k*t/50), row 2k+1 = sin(...),
// rows 52..63 = 0, t 50..63 = 0. One block = one (b,c) x 256 pixels.
// LDS layouts are fragment-native 16B chunks [t8][row] so ds_read_b128 is
// conflict-light. Each lane's 4 acc regs are the (cos,sin) pairs for 2 bins.
// Writes f[(b*HW+hw)*416 + c*26 + k] (bf16) directly (packed dword stores).
// ---------------------------------------------------------------------------
__global__ __launch_bounds__(256) void dft_mfma_kernel(
    const __half* __restrict__ yseq, __hip_bfloat16* __restrict__ f)
{
    __shared__ char Ys[8*256*16];   // chunk ci = t8*256 + p  -> Y[p][t8*8..+7]
    __shared__ char Gs[8*64*16];    // chunk ci = t8*64  + r  -> G[r][t8*8..+7]
    const int tid = threadIdx.x;
    const int blk = blockIdx.x;        // bc*16 + ptile
    const int bc  = blk >> 4;
    const int p0  = (blk & 15) << 8;
    const int b   = bc >> 4, c = bc & 15;

    // build basis (4096 f16 entries, 16/thread)
    for (int idx = tid; idx < 64*64; idx += 256){
        int r = idx >> 6, t = idx & 63;
        float v = 0.f;
        if (r < 52 && t < 50){
            int k  = r >> 1;
            int ph = (k * t) % 50;
            float ang = (float)ph * (6.2831853071795864f / 50.f);
            v = (r & 1) ? sinf(ang) : cosf(ang);
        }
        *(_Float16*)(Gs + ((t >> 3)*64 + r)*16 + (t & 7)*2) = (_Float16)v;
    }

    // stage Y: thread owns pixel p = tid; 50 coalesced 2B loads, packed dwords
    {
        const __half* src = yseq + (size_t)bc*HW_ + p0 + tid;
        #pragma unroll
        for (int t2 = 0; t2 < 25; t2++){
            unsigned int a = *(const unsigned short*)&src[(size_t)(2*t2)*BCHW_];
            unsigned int d = *(const unsigned short*)&src[(size_t)(2*t2+1)*BCHW_];
            int t8 = t2 >> 2, j = t2 & 3;
            *(unsigned int*)(Ys + (t8*256 + tid)*16 + j*4) = a | (d << 16);
        }
        #pragma unroll
        for (int t2 = 25; t2 < 32; t2++){
            int t8 = t2 >> 2, j = t2 & 3;
            *(unsigned int*)(Ys + (t8*256 + tid)*16 + j*4) = 0u;
        }
    }
    __syncthreads();

    const int lane = tid & 63;
    const int w    = tid >> 6;          // m-tile: bins rows 16w..16w+15
    const int n    = lane & 15;
    const int quad = lane >> 4;
    const int mrow = 16*w + n;

    f16x8 a0 = *(const f16x8*)(Gs + ((quad    )*64 + mrow)*16);
    f16x8 a1 = *(const f16x8*)(Gs + ((quad + 4)*64 + mrow)*16);

    // lane's 4 acc rows = 16w + quad*4 + {0,1,2,3} = bins (8w+2q, 8w+2q+1)
    const int kb0   = 8*w + 2*quad;
    const bool valid = (kb0 < K_);      // masks w==3, quad>=1 pad rows

    for (int nt = 0; nt < 16; nt++){
        f16x8 b0 = *(const f16x8*)(Ys + ((quad    )*256 + nt*16 + n)*16);
        f16x8 b1 = *(const f16x8*)(Ys + ((quad + 4)*256 + nt*16 + n)*16);
        f32x4 acc = (f32x4){0.f, 0.f, 0.f, 0.f};
        acc = __builtin_amdgcn_mfma_f32_16x16x32_f16(a0, b0, acc, 0, 0, 0);
        acc = __builtin_amdgcn_mfma_f32_16x16x32_f16(a1, b1, acc, 0, 0, 0);
        if (valid){
            float m0 = sqrtf(fmaf(acc[0], acc[0], acc[1]*acc[1]));
            float m1 = sqrtf(fmaf(acc[2], acc[2], acc[3]*acc[3]));
            __hip_bfloat16 h0 = __float2bfloat16(m0);
            __hip_bfloat16 h1 = __float2bfloat16(m1);
            unsigned int u = ((unsigned int)*(unsigned short*)&h1 << 16)
                           |  (unsigned int)*(unsigned short*)&h0;
            const int row = b*HW_ + p0 + nt*16 + n;
            *(unsigned int*)((char*)(f + (size_t)row*F_ + c*K_) + kb0*2) = u;
        }
    }
}

// ---------------------------------------------------------------------------
// Weight prep: w[K][N] fp32 -> wt[N][K] bf16
// ---------------------------------------------------------------------------
__global__ __launch_bounds__(256) void prep_wt_kernel(
    const float* __restrict__ w, __hip_bfloat16* __restrict__ wt, int Kd, int N)
{
    const int n = blockIdx.x;
    for (int k = threadIdx.x; k < Kd; k += 256)
        wt[(size_t)n*Kd + k] = __float2bfloat16(w[(size_t)k*N + n]);
}

// ---------------------------------------------------------------------------
// MFMA GEMM: C = relu(A @ W + bias), bf16 in / fp32 acc / bf16 out.
// ---------------------------------------------------------------------------
__global__ __launch_bounds__(256) void gemm_mfma_kernel(
    const __hip_bfloat16* __restrict__ A, const __hip_bfloat16* __restrict__ Wt,
    const float* __restrict__ bias, __hip_bfloat16* __restrict__ C,
    int M, int N, int Kd)
{
    __shared__ short As[128*32];
    __shared__ short Bs[128*32];
    const int tid  = threadIdx.x;
    const int lane = tid & 63;
    const int wave = tid >> 6;
    const int wm = (wave & 1) * 64;
    const int wn = (wave >> 1) * 64;
    const int m0 = blockIdx.x * 128;
    const int n0 = blockIdx.y * 128;

    f32x4 acc[4][4];
    #pragma unroll
    for (int i = 0; i < 4; i++)
        #pragma unroll
        for (int j = 0; j < 4; j++)
            acc[i][j] = (f32x4){0.f, 0.f, 0.f, 0.f};

    const int rloc = tid >> 2;
    const int kc   = (tid & 3) * 8;
    const char* Ag = (const char*)(A  + (size_t)(m0 + rloc)*Kd + kc);
    const char* Bg = (const char*)(Wt + (size_t)(n0 + rloc)*Kd + kc);
    const size_t rstride = (size_t)64 * Kd * 2;
    char* AsB = (char*)As + tid*16;
    char* BsB = (char*)Bs + tid*16;

    const int fa = (wm + (lane & 15)) * 32 + (lane >> 4) * 8;
    const int fb = (wn + (lane & 15)) * 32 + (lane >> 4) * 8;

    for (int k0 = 0; k0 < Kd; k0 += 32){
        const char* ag = Ag + (size_t)k0 * 2;
        const char* bg = Bg + (size_t)k0 * 2;
        gld_lds16(ag,           AsB);
        gld_lds16(ag + rstride, AsB + 4096);
        gld_lds16(bg,           BsB);
        gld_lds16(bg + rstride, BsB + 4096);
        __syncthreads();

        bf16x8 af[4], bfv[4];
        #pragma unroll
        for (int i = 0; i < 4; i++){
            af[i]  = *(const bf16x8*)&As[fa + i*16*32];
            bfv[i] = *(const bf16x8*)&Bs[fb + i*16*32];
        }
        #pragma unroll
        for (int i = 0; i < 4; i++)
            #pragma unroll
            for (int j = 0; j < 4; j++)
                acc[i][j] = __builtin_amdgcn_mfma_f32_16x16x32_bf16(
                                af[i], bfv[j], acc[i][j], 0, 0, 0);
        __syncthreads();
    }

    const int colb = n0 + wn + (lane & 15);
    const int rowb = m0 + wm + ((lane >> 4) << 2);
    #pragma unroll
    for (int j = 0; j < 4; j++){
        const int col = colb + j*16;
        const float bv = bias[col];
        #pragma unroll
        for (int i = 0; i < 4; i++){
            const int row0 = rowb + i*16;
            #pragma unroll
            for (int r = 0; r < 4; r++){
                float v = acc[i][j][r] + bv;
                v = fmaxf(v, 0.f);
                C[(size_t)(row0 + r)*N + col] = __float2bfloat16(v);
            }
        }
    }
}

// ---------------------------------------------------------------------------
// Final layer 256->7 (bf16 input) fused with (BHW,7)->(B,7,H,W) transpose.
// ---------------------------------------------------------------------------
__global__ __launch_bounds__(256) void final_kernel(
    const __hip_bfloat16* __restrict__ h, const float* __restrict__ w,
    const float* __restrict__ bias, float* __restrict__ out)
{
    __shared__ float wsm[HID_*NC_];
    __shared__ float bs[NC_];
    const int tid = threadIdx.x;
    for (int i = tid; i < HID_*NC_; i += 256) wsm[i] = w[i];
    if (tid < NC_) bs[tid] = bias[tid];
    __syncthreads();

    const int row = blockIdx.x*256 + tid;
    const uint4* hp = (const uint4*)(h + (size_t)row*HID_);
    float acc[NC_];
    #pragma unroll
    for (int j = 0; j < NC_; j++) acc[j] = bs[j];

    for (int k8 = 0; k8 < HID_/8; k8++){
        uint4 u = hp[k8];
        float v[8];
        v[0] = __uint_as_float(u.x << 16); v[1] = __uint_as_float(u.x & 0xffff0000u);
        v[2] = __uint_as_float(u.y << 16); v[3] = __uint_as_float(u.y & 0xffff0000u);
        v[4] = __uint_as_float(u.z << 16); v[5] = __uint_as_float(u.z & 0xffff0000u);
        v[6] = __uint_as_float(u.w << 16); v[7] = __uint_as_float(u.w & 0xffff0000u);
        const int k = k8*8;
        #pragma unroll
        for (int e = 0; e < 8; e++){
            #pragma unroll
            for (int j = 0; j < NC_; j++)
                acc[j] = fmaf(v[e], wsm[(k+e)*NC_ + j], acc[j]);
        }
    }
    const int b = row >> 12, hw = row & 4095;
    #pragma unroll
    for (int j = 0; j < NC_; j++)
        out[(size_t)(b*NC_ + j)*HW_ + hw] = acc[j];
}

// ---------------------------------------------------------------------------
// Workspace (peak 159,383,552 B, proven):
//   yseq fp16 [50][256][4096] @ 0 (104,857,600)         ODE w, DFT r
//   fbuf bf16 [65536][416] @ 104,857,600 (54,525,952)   DFT w, GEMM1 r
//     conv temps (10 x 4 MiB) aliased in fbuf region (dead before DFT)
//   h1/h2/h3 bf16 + wt1/2/3 in yseq region after DFT.
// ---------------------------------------------------------------------------
extern "C" void kernel_launch(void* const* d_in, const int* in_sizes, int n_in,
                              void* d_out, int out_size, void* d_ws, size_t ws_size,
                              hipStream_t stream)
{
    const float* x     = (const float*)d_in[0];
    const float* om_w1 = (const float*)d_in[1];  const float* om_b1 = (const float*)d_in[2];
    const float* om_w2 = (const float*)d_in[3];  const float* om_b2 = (const float*)d_in[4];
    const float* om_w3 = (const float*)d_in[5];  const float* om_b3 = (const float*)d_in[6];
    const float* al_w1 = (const float*)d_in[7];  const float* al_b1 = (const float*)d_in[8];
    const float* al_w2 = (const float*)d_in[9];  const float* al_b2 = (const float*)d_in[10];
    const float* al_w3 = (const float*)d_in[11]; const float* al_b3 = (const float*)d_in[12];
    const float* hy_w1 = (const float*)d_in[13]; const float* hy_b1 = (const float*)d_in[14];
    const float* hy_w2 = (const float*)d_in[15]; const float* hy_b2 = (const float*)d_in[16];
    const float* hy_w3 = (const float*)d_in[17]; const float* hy_b3 = (const float*)d_in[18];
    const float* hy_w4 = (const float*)d_in[19]; const float* hy_b4 = (const float*)d_in[20];
    const float* wy    = (const float*)d_in[21];
    const float* ro_w1 = (const float*)d_in[22]; const float* ro_b1 = (const float*)d_in[23];
    const float* ro_w2 = (const float*)d_in[24]; const float* ro_b2 = (const float*)d_in[25];
    const float* ro_w3 = (const float*)d_in[26]; const float* ro_b3 = (const float*)d_in[27];
    const float* ro_w4 = (const float*)d_in[28]; const float* ro_b4 = (const float*)d_in[29];
    float* out = (float*)d_out;

    char* wsb = (char*)d_ws;
    const size_t YSEQ_BYTES = (size_t)T_ * BCHW_ * 2;          // 104,857,600
    __half* yseq = (__half*)wsb;
    __hip_bfloat16* fbuf = (__hip_bfloat16*)(wsb + YSEQ_BYTES);

    const size_t MB4 = (size_t)BCHW_ * 4;                      // 4 MiB
    float* om_t1 = (float*)(wsb + YSEQ_BYTES + 0*MB4);
    float* al_t1 = (float*)(wsb + YSEQ_BYTES + 1*MB4);
    float* hy_t1 = (float*)(wsb + YSEQ_BYTES + 2*MB4);
    float* om_t2 = (float*)(wsb + YSEQ_BYTES + 3*MB4);
    float* al_t2 = (float*)(wsb + YSEQ_BYTES + 4*MB4);
    float* hy_t2 = (float*)(wsb + YSEQ_BYTES + 5*MB4);
    float* omega = (float*)(wsb + YSEQ_BYTES + 6*MB4);
    float* alpha = (float*)(wsb + YSEQ_BYTES + 7*MB4);
    float* hy_t3 = (float*)(wsb + YSEQ_BYTES + 8*MB4);
    float* hy0   = (float*)(wsb + YSEQ_BYTES + 9*MB4);

    const size_t HB = (size_t)M_ * HID_ * 2;                   // 33,554,432
    __hip_bfloat16* h1 = (__hip_bfloat16*)(wsb + 0);
    __hip_bfloat16* h2 = (__hip_bfloat16*)(wsb + HB);
    __hip_bfloat16* h3 = (__hip_bfloat16*)(wsb + 2*HB);
    __hip_bfloat16* wt1 = (__hip_bfloat16*)(wsb + 3*HB);
    __hip_bfloat16* wt2 = (__hip_bfloat16*)(wsb + 3*HB + 212992);
    __hip_bfloat16* wt3 = (__hip_bfloat16*)(wsb + 3*HB + 344064);

    // encoders: 3 chains fused per layer
    convf_kernel<1,0><<<dim3(4,B_,3), 1024, 0, stream>>>(
        x, x, x, om_w1, al_w1, hy_w1, om_b1, al_b1, hy_b1, om_t1, al_t1, hy_t1);
    convf_kernel<16,0><<<dim3(4,B_,3), 1024, 0, stream>>>(
        om_t1, al_t1, hy_t1, om_w2, al_w2, hy_w2, om_b2, al_b2, hy_b2, om_t2, al_t2, hy_t2);
    convf_kernel<16,0><<<dim3(4,B_,3), 1024, 0, stream>>>(
        om_t2, al_t2, hy_t2, om_w3, al_w3, hy_w3, om_b3, al_b3, hy_b3, omega, alpha, hy_t3);
    convf_kernel<16,1><<<dim3(4,B_,1), 1024, 0, stream>>>(
        hy_t3, hy_t3, hy_t3, hy_w4, hy_w4, hy_w4, hy_b4, hy_b4, hy_b4, hy0, hy0, hy0);
    // 50-step ODE (fp16 yseq out)
    ode_kernel<<<256, 1024, 0, stream>>>(omega, alpha, hy0, wy, yseq);
    // MFMA DFT: rfft magnitude -> row-major bf16 features
    dft_mfma_kernel<<<4096, 256, 0, stream>>>(yseq, fbuf);
    // weight transposes (yseq dead; wt in its tail region)
    prep_wt_kernel<<<256, 256, 0, stream>>>(ro_w1, wt1, F_,   HID_);
    prep_wt_kernel<<<256, 256, 0, stream>>>(ro_w2, wt2, HID_, HID_);
    prep_wt_kernel<<<256, 256, 0, stream>>>(ro_w3, wt3, HID_, HID_);
    // readout MLP (MFMA)
    gemm_mfma_kernel<<<dim3(512,2), 256, 0, stream>>>(fbuf, wt1, ro_b1, h1, M_, HID_, F_);
    gemm_mfma_kernel<<<dim3(512,2), 256, 0, stream>>>(h1,   wt2, ro_b2, h2, M_, HID_, HID_);
    gemm_mfma_kernel<<<dim3(512,2), 256, 0, stream>>>(h2,   wt3, ro_b3, h3, M_, HID_, HID_);
    final_kernel<<<256, 256, 0, stream>>>(h3, ro_w4, ro_b4, out);
}

// Round 7
// 413.946 us; speedup vs baseline: 14.7768x; 1.0568x over previous
//
#include <hip/hip_runtime.h>
#include <hip/hip_bf16.h>
#include <hip/hip_fp16.h>
#include <math.h>

#define B_   16
#define C_   16
#define S_   64
#define HW_  4096
#define T_   50
#define K_   26
#define F_   416   // C_*K_
#define HID_ 256
#define NC_  7
#define DT_  0.5f
#define BCHW_ (B_*C_*HW_)
#define M_   (B_*HW_)   // 65536 rows into the MLP

typedef short    bf16x8 __attribute__((ext_vector_type(8)));
typedef _Float16 f16x8  __attribute__((ext_vector_type(8)));
typedef float    f32x4  __attribute__((ext_vector_type(4)));

__device__ __forceinline__ void gld_lds16(const void* g, void* l){
    __builtin_amdgcn_global_load_lds(
        (const __attribute__((address_space(1))) void*)g,
        (__attribute__((address_space(3))) void*)l, 16, 0, 0);
}

__device__ __forceinline__ float fast_tanh(float x){
    float ax = fabsf(x);
    float e  = __expf(2.f*ax);
    float r  = 1.f - 2.f/(e + 1.f);
    return copysignf(r, x);
}

__device__ __forceinline__ float b2f(short s){
    return __uint_as_float(((unsigned int)(unsigned short)s) << 16);
}
__device__ __forceinline__ short f2b(float f){
    __hip_bfloat16 h = __float2bfloat16(f);
    return *(short*)&h;
}

// ---------------------------------------------------------------------------
// Fused multi-chain 3x3 conv, zero 'SAME' padding. (unchanged)
// ---------------------------------------------------------------------------
template<int CIN, int ACT>
__global__ __launch_bounds__(1024) void convf_kernel(
    const float* __restrict__ in0, const float* __restrict__ in1, const float* __restrict__ in2,
    const float* __restrict__ w0,  const float* __restrict__ w1,  const float* __restrict__ w2,
    const float* __restrict__ b0,  const float* __restrict__ b1,  const float* __restrict__ b2,
    float* __restrict__ o0, float* __restrict__ o1, float* __restrict__ o2)
{
    __shared__ float slab[CIN][18][66];
    const int slice = blockIdx.x;
    const int b     = blockIdx.y;
    const int ch    = blockIdx.z;
    const float* in = (ch == 0) ? in0 : (ch == 1) ? in1 : in2;
    const float* w  = (ch == 0) ? w0  : (ch == 1) ? w1  : w2;
    const float* bb = (ch == 0) ? b0  : (ch == 1) ? b1  : b2;
    float* out      = (ch == 0) ? o0  : (ch == 1) ? o1  : o2;

    const int tid = threadIdx.x;
    const int y0  = slice * 16;

    for (int idx = tid; idx < CIN*18*66; idx += 1024){
        int ci  = idx / (18*66);
        int rem = idx % (18*66);
        int rr  = rem / 66;
        int cc  = rem % 66;
        int gy = y0 - 1 + rr;
        int gx = cc - 1;
        float v = 0.f;
        if ((unsigned)gy < 64u && (unsigned)gx < 64u)
            v = in[(size_t)(b*CIN + ci)*HW_ + gy*64 + gx];
        slab[ci][rr][cc] = v;
    }
    __syncthreads();

    const int x  = tid & 63;
    const int ry = tid >> 6;

    float acc[16];
    #pragma unroll
    for (int co = 0; co < 16; co++) acc[co] = bb[co];

    for (int ci = 0; ci < CIN; ci++){
        float p[3][3];
        #pragma unroll
        for (int dy = 0; dy < 3; dy++)
            #pragma unroll
            for (int dx = 0; dx < 3; dx++)
                p[dy][dx] = slab[ci][ry + dy][x + dx];
        #pragma unroll
        for (int co = 0; co < 16; co++){
            const float* wp = w + (size_t)(co*CIN + ci)*9;
            float s = acc[co];
            #pragma unroll
            for (int dy = 0; dy < 3; dy++)
                #pragma unroll
                for (int dx = 0; dx < 3; dx++)
                    s = fmaf(wp[dy*3 + dx], p[dy][dx], s);
            acc[co] = s;
        }
    }
    #pragma unroll
    for (int co = 0; co < 16; co++){
        float v = acc[co];
        v = ACT ? fast_tanh(v) : fmaxf(v, 0.f);
        out[(size_t)(b*16 + co)*HW_ + (y0 + ry)*64 + x] = v;
    }
}

// ---------------------------------------------------------------------------
// 50-step coRNN ODE with uniform 5-point fast path (wy is a Laplacian:
// corner taps are zero -> checked at runtime, wave-uniform branch).
// Output yseq fp16 [t][bc][hw].
// ---------------------------------------------------------------------------
__global__ __launch_bounds__(1024) void ode_kernel(
    const float* __restrict__ omega, const float* __restrict__ alpha,
    const float* __restrict__ hy0,   const float* __restrict__ wy,
    __half* __restrict__ yseq)
{
    __shared__ float buf[2][64*65];
    const int blk = blockIdx.x;            // b*16 + c
    const int c   = blk & 15;
    const int tid = threadIdx.x;
    const int x   = tid & 63;
    const int sy  = (tid >> 6) << 2;       // 0,4,...,60
    const size_t off = (size_t)blk * HW_;

    float om[4], al[4], hz[4], hy[4];
    #pragma unroll
    for (int i = 0; i < 4; i++){
        size_t g = off + (size_t)(sy + i)*64 + x;
        om[i] = omega[g];
        al[i] = alpha[g];
        hz[i] = 0.f;
        hy[i] = hy0[g];
        buf[0][x*65 + sy + i] = hy[i];
    }
    float wv[9];
    const float* wp = wy + (size_t)(c*C_ + c)*9;
    #pragma unroll
    for (int j = 0; j < 9; j++) wv[j] = wp[j];
    const bool five = (wv[0]==0.f) & (wv[2]==0.f) & (wv[6]==0.f) & (wv[8]==0.f);
    __syncthreads();

    const int xl = ((x + 63) & 63) * 65;
    const int xr = ((x + 1)  & 63) * 65;
    const int xo = x * 65;
    const int ylo = (sy + 63) & 63;
    const int yhi = (sy + 4)  & 63;

    int cur = 0;
    for (int t = 0; t < T_; t++){
        const float* hp = buf[cur];
        float* hn = buf[cur ^ 1];
        float l[6], r[6];
        #pragma unroll
        for (int i = 0; i < 4; i++){ l[i+1] = hp[xl + sy + i]; r[i+1] = hp[xr + sy + i]; }
        if (!five){
            l[0] = hp[xl + ylo];  r[0] = hp[xr + ylo];
            l[5] = hp[xl + yhi];  r[5] = hp[xr + yhi];
        }
        float tN = hp[xo + ylo];
        float tS = hp[xo + yhi];

        __half* yout = yseq + (size_t)t*BCHW_ + off;
        float ny[4];
        #pragma unroll
        for (int i = 0; i < 4; i++){
            float up = (i == 0) ? tN : hy[i-1];
            float dn = (i == 3) ? tS : hy[i+1];
            float s = wv[1]*up + wv[3]*l[i+1] + wv[4]*hy[i] + wv[5]*r[i+1] + wv[7]*dn;
            if (!five)
                s += wv[0]*l[i] + wv[2]*r[i] + wv[6]*l[i+2] + wv[8]*r[i+2];
            float sf = fast_tanh(s);
            float nz = hz[i] + DT_*(sf - om[i]*hy[i] - al[i]*hz[i]);
            float v  = hy[i] + DT_*nz;
            hz[i] = nz;
            ny[i] = v;
        }
        #pragma unroll
        for (int i = 0; i < 4; i++){
            hy[i] = ny[i];
            hn[xo + sy + i] = ny[i];
            yout[(sy + i)*64 + x] = __float2half(ny[i]);
        }
        __syncthreads();
        cur ^= 1;
    }
}

// ---------------------------------------------------------------------------
// MFMA DFT (unchanged from round 6).
// ---------------------------------------------------------------------------
__global__ __launch_bounds__(256) void dft_mfma_kernel(
    const __half* __restrict__ yseq, __hip_bfloat16* __restrict__ f)
{
    __shared__ char Ys[8*256*16];
    __shared__ char Gs[8*64*16];
    const int tid = threadIdx.x;
    const int blk = blockIdx.x;
    const int bc  = blk >> 4;
    const int p0  = (blk & 15) << 8;
    const int b   = bc >> 4, c = bc & 15;

    for (int idx = tid; idx < 64*64; idx += 256){
        int r = idx >> 6, t = idx & 63;
        float v = 0.f;
        if (r < 52 && t < 50){
            int k  = r >> 1;
            int ph = (k * t) % 50;
            float ang = (float)ph * (6.2831853071795864f / 50.f);
            v = (r & 1) ? sinf(ang) : cosf(ang);
        }
        *(_Float16*)(Gs + ((t >> 3)*64 + r)*16 + (t & 7)*2) = (_Float16)v;
    }

    {
        const __half* src = yseq + (size_t)bc*HW_ + p0 + tid;
        #pragma unroll
        for (int t2 = 0; t2 < 25; t2++){
            unsigned int a = *(const unsigned short*)&src[(size_t)(2*t2)*BCHW_];
            unsigned int d = *(const unsigned short*)&src[(size_t)(2*t2+1)*BCHW_];
            int t8 = t2 >> 2, j = t2 & 3;
            *(unsigned int*)(Ys + (t8*256 + tid)*16 + j*4) = a | (d << 16);
        }
        #pragma unroll
        for (int t2 = 25; t2 < 32; t2++){
            int t8 = t2 >> 2, j = t2 & 3;
            *(unsigned int*)(Ys + (t8*256 + tid)*16 + j*4) = 0u;
        }
    }
    __syncthreads();

    const int lane = tid & 63;
    const int w    = tid >> 6;
    const int n    = lane & 15;
    const int quad = lane >> 4;
    const int mrow = 16*w + n;

    f16x8 a0 = *(const f16x8*)(Gs + ((quad    )*64 + mrow)*16);
    f16x8 a1 = *(const f16x8*)(Gs + ((quad + 4)*64 + mrow)*16);

    const int kb0   = 8*w + 2*quad;
    const bool valid = (kb0 < K_);

    for (int nt = 0; nt < 16; nt++){
        f16x8 b0 = *(const f16x8*)(Ys + ((quad    )*256 + nt*16 + n)*16);
        f16x8 b1 = *(const f16x8*)(Ys + ((quad + 4)*256 + nt*16 + n)*16);
        f32x4 acc = (f32x4){0.f, 0.f, 0.f, 0.f};
        acc = __builtin_amdgcn_mfma_f32_16x16x32_f16(a0, b0, acc, 0, 0, 0);
        acc = __builtin_amdgcn_mfma_f32_16x16x32_f16(a1, b1, acc, 0, 0, 0);
        if (valid){
            float m0 = sqrtf(fmaf(acc[0], acc[0], acc[1]*acc[1]));
            float m1 = sqrtf(fmaf(acc[2], acc[2], acc[3]*acc[3]));
            unsigned int u = ((unsigned int)(unsigned short)f2b(m1) << 16)
                           |  (unsigned int)(unsigned short)f2b(m0);
            const int row = b*HW_ + p0 + nt*16 + n;
            *(unsigned int*)((char*)(f + (size_t)row*F_ + c*K_) + kb0*2) = u;
        }
    }
}

// ---------------------------------------------------------------------------
// Weight prep: w[K][N] fp32 -> wt[N][K] bf16
// ---------------------------------------------------------------------------
__global__ __launch_bounds__(256) void prep_wt_kernel(
    const float* __restrict__ w, __hip_bfloat16* __restrict__ wt, int Kd, int N)
{
    const int n = blockIdx.x;
    for (int k = threadIdx.x; k < Kd; k += 256)
        wt[(size_t)n*Kd + k] = __float2bfloat16(w[(size_t)k*N + n]);
}

// ---------------------------------------------------------------------------
// FUSED MLP: relu(relu(relu(A@W1+b1)@W2+b2)@W3+b3)@W4+b4 -> out (NCHW).
// One block = 256-row tile, 512 threads = 8 waves (wave grid 4m x 2n, each
// 64x128). Layer-1 A-frags direct from global (prefetched); h kept in LDS
// bf16 (rows padded to 258 shorts: stride 129 dwords == 1 mod 32 ->
// conflict-free A-frag reads). B k-tiles staged via global_load_lds into a
// chunk-permuted [kc][n] layout (lane-linear DMA dst, conflict-free reads).
// ---------------------------------------------------------------------------
__global__ __launch_bounds__(512, 2) void mlp_fused_kernel(
    const __hip_bfloat16* __restrict__ A,     // fbuf [M][416]
    const __hip_bfloat16* __restrict__ Wt1,   // [256][416]
    const __hip_bfloat16* __restrict__ Wt2,   // [256][256]
    const __hip_bfloat16* __restrict__ Wt3,   // [256][256]
    const float* __restrict__ b1, const float* __restrict__ b2,
    const float* __restrict__ b3,
    const float* __restrict__ w4, const float* __restrict__ b4,
    float* __restrict__ out)
{
    __shared__ short hbuf[256*258];   // 132,096 B
    __shared__ short Bs[1024*8];      // 16,384 B : chunk (kc,n) at (kc*256+n)*8
    __shared__ float w4s[HID_*NC_];   // 7,168 B

    const int tid  = threadIdx.x;
    const int lane = tid & 63;
    const int wave = tid >> 6;
    const int wm   = (wave & 3) * 64;
    const int wn   = (wave >> 2) * 128;
    const int n16  = lane & 15;
    const int quad = lane >> 4;
    const int m0   = blockIdx.x * 256;

    for (int i = tid; i < HID_*NC_; i += 512) w4s[i] = w4[i];

    // staging ids: chunk id -> (kc = id>>8, n = id&255); dst byte = id*16
    const int id0 = tid, id1 = tid + 512;
    const int kc0 = id0 >> 8, nn0 = id0 & 255;
    const int kc1 = id1 >> 8, nn1 = id1 & 255;

    f32x4 acc[4][8];
    #pragma unroll
    for (int i = 0; i < 4; i++)
        #pragma unroll
        for (int j = 0; j < 8; j++)
            acc[i][j] = (f32x4){0.f,0.f,0.f,0.f};

    // ---------------- layer 1: A from global ----------------
    const __hip_bfloat16* arow[4];
    #pragma unroll
    for (int i = 0; i < 4; i++)
        arow[i] = A + (size_t)(m0 + wm + i*16 + n16)*F_ + quad*8;

    bf16x8 afn[4];
    #pragma unroll
    for (int i = 0; i < 4; i++) afn[i] = *(const bf16x8*)(arow[i]);

    for (int k0 = 0; k0 < F_; k0 += 32){
        gld_lds16(Wt1 + (size_t)nn0*F_ + k0 + kc0*8, (char*)Bs + id0*16);
        gld_lds16(Wt1 + (size_t)nn1*F_ + k0 + kc1*8, (char*)Bs + id1*16);
        __syncthreads();
        bf16x8 af[4];
        #pragma unroll
        for (int i = 0; i < 4; i++) af[i] = afn[i];
        if (k0 + 32 < F_){
            #pragma unroll
            for (int i = 0; i < 4; i++) afn[i] = *(const bf16x8*)(arow[i] + k0 + 32);
        }
        bf16x8 bf[8];
        #pragma unroll
        for (int j = 0; j < 8; j++)
            bf[j] = *(const bf16x8*)&Bs[(quad*256 + wn + j*16 + n16)*8];
        #pragma unroll
        for (int i = 0; i < 4; i++)
            #pragma unroll
            for (int j = 0; j < 8; j++)
                acc[i][j] = __builtin_amdgcn_mfma_f32_16x16x32_bf16(
                                af[i], bf[j], acc[i][j], 0, 0, 0);
        __syncthreads();
    }
    // epilogue: C/D col=lane&15 (within j-tile), row=quad*4+r (within i-tile)
    #pragma unroll
    for (int j = 0; j < 8; j++){
        const int col = wn + j*16 + n16;
        const float bv = b1[col];
        #pragma unroll
        for (int i = 0; i < 4; i++){
            const int r0 = wm + i*16 + quad*4;
            #pragma unroll
            for (int r = 0; r < 4; r++)
                hbuf[(r0 + r)*258 + col] = f2b(fmaxf(acc[i][j][r] + bv, 0.f));
        }
    }
    __syncthreads();

    // ---------------- layers 2,3: A from hbuf ----------------
    const __hip_bfloat16* Wts[2] = {Wt2, Wt3};
    const float* bls[2] = {b2, b3};
    for (int L = 0; L < 2; L++){
        const __hip_bfloat16* Wt = Wts[L];
        #pragma unroll
        for (int i = 0; i < 4; i++)
            #pragma unroll
            for (int j = 0; j < 8; j++)
                acc[i][j] = (f32x4){0.f,0.f,0.f,0.f};

        for (int k0 = 0; k0 < HID_; k0 += 32){
            gld_lds16(Wt + (size_t)nn0*HID_ + k0 + kc0*8, (char*)Bs + id0*16);
            gld_lds16(Wt + (size_t)nn1*HID_ + k0 + kc1*8, (char*)Bs + id1*16);
            bf16x8 af[4];
            #pragma unroll
            for (int i = 0; i < 4; i++)
                af[i] = *(const bf16x8*)&hbuf[(wm + i*16 + n16)*258 + k0 + quad*8];
            __syncthreads();
            bf16x8 bf[8];
            #pragma unroll
            for (int j = 0; j < 8; j++)
                bf[j] = *(const bf16x8*)&Bs[(quad*256 + wn + j*16 + n16)*8];
            #pragma unroll
            for (int i = 0; i < 4; i++)
                #pragma unroll
                for (int j = 0; j < 8; j++)
                    acc[i][j] = __builtin_amdgcn_mfma_f32_16x16x32_bf16(
                                    af[i], bf[j], acc[i][j], 0, 0, 0);
            __syncthreads();
        }
        const float* bl = bls[L];
        #pragma unroll
        for (int j = 0; j < 8; j++){
            const int col = wn + j*16 + n16;
            const float bv = bl[col];
            #pragma unroll
            for (int i = 0; i < 4; i++){
                const int r0 = wm + i*16 + quad*4;
                #pragma unroll
                for (int r = 0; r < 4; r++)
                    hbuf[(r0 + r)*258 + col] = f2b(fmaxf(acc[i][j][r] + bv, 0.f));
            }
        }
        __syncthreads();
    }

    // ---------------- final layer 256 -> 7 + NCHW transpose ----------------
    const int row = tid >> 1;
    const int sel = tid & 1;
    const int j0  = sel ? 4 : 0;
    const int nj  = sel ? 3 : 4;

    float facc[4];
    #pragma unroll
    for (int t = 0; t < 4; t++) facc[t] = (t < nj) ? b4[j0 + t] : 0.f;

    for (int k8 = 0; k8 < HID_/8; k8++){
        bf16x8 hv = *(const bf16x8*)&hbuf[row*258 + k8*8];
        #pragma unroll
        for (int e = 0; e < 8; e++){
            float vv = b2f(hv[e]);
            const float* wr = &w4s[(k8*8 + e)*NC_ + j0];
            #pragma unroll
            for (int t = 0; t < 4; t++)
                if (t < nj) facc[t] = fmaf(vv, wr[t], facc[t]);
        }
    }
    const int grow = m0 + row;
    const int bidx = grow >> 12, hw = grow & 4095;
    #pragma unroll
    for (int t = 0; t < 4; t++)
        if (t < nj)
            out[(size_t)(bidx*NC_ + j0 + t)*HW_ + hw] = facc[t];
}

// ---------------------------------------------------------------------------
// Workspace (peak 159,383,552 B, proven):
//   yseq fp16 [50][256][4096] @ 0 (104,857,600)         ODE w, DFT r
//   fbuf bf16 [65536][416] @ 104,857,600 (54,525,952)   DFT w, MLP r
//     conv temps (10 x 4 MiB) aliased in fbuf region (dead before DFT)
//   wt1/2/3 bf16 @ 0 (yseq region, dead after DFT)
// ---------------------------------------------------------------------------
extern "C" void kernel_launch(void* const* d_in, const int* in_sizes, int n_in,
                              void* d_out, int out_size, void* d_ws, size_t ws_size,
                              hipStream_t stream)
{
    const float* x     = (const float*)d_in[0];
    const float* om_w1 = (const float*)d_in[1];  const float* om_b1 = (const float*)d_in[2];
    const float* om_w2 = (const float*)d_in[3];  const float* om_b2 = (const float*)d_in[4];
    const float* om_w3 = (const float*)d_in[5];  const float* om_b3 = (const float*)d_in[6];
    const float* al_w1 = (const float*)d_in[7];  const float* al_b1 = (const float*)d_in[8];
    const float* al_w2 = (const float*)d_in[9];  const float* al_b2 = (const float*)d_in[10];
    const float* al_w3 = (const float*)d_in[11]; const float* al_b3 = (const float*)d_in[12];
    const float* hy_w1 = (const float*)d_in[13]; const float* hy_b1 = (const float*)d_in[14];
    const float* hy_w2 = (const float*)d_in[15]; const float* hy_b2 = (const float*)d_in[16];
    const float* hy_w3 = (const float*)d_in[17]; const float* hy_b3 = (const float*)d_in[18];
    const float* hy_w4 = (const float*)d_in[19]; const float* hy_b4 = (const float*)d_in[20];
    const float* wy    = (const float*)d_in[21];
    const float* ro_w1 = (const float*)d_in[22]; const float* ro_b1 = (const float*)d_in[23];
    const float* ro_w2 = (const float*)d_in[24]; const float* ro_b2 = (const float*)d_in[25];
    const float* ro_w3 = (const float*)d_in[26]; const float* ro_b3 = (const float*)d_in[27];
    const float* ro_w4 = (const float*)d_in[28]; const float* ro_b4 = (const float*)d_in[29];
    float* out = (float*)d_out;

    char* wsb = (char*)d_ws;
    const size_t YSEQ_BYTES = (size_t)T_ * BCHW_ * 2;          // 104,857,600
    __half* yseq = (__half*)wsb;
    __hip_bfloat16* fbuf = (__hip_bfloat16*)(wsb + YSEQ_BYTES);

    const size_t MB4 = (size_t)BCHW_ * 4;                      // 4 MiB
    float* om_t1 = (float*)(wsb + YSEQ_BYTES + 0*MB4);
    float* al_t1 = (float*)(wsb + YSEQ_BYTES + 1*MB4);
    float* hy_t1 = (float*)(wsb + YSEQ_BYTES + 2*MB4);
    float* om_t2 = (float*)(wsb + YSEQ_BYTES + 3*MB4);
    float* al_t2 = (float*)(wsb + YSEQ_BYTES + 4*MB4);
    float* hy_t2 = (float*)(wsb + YSEQ_BYTES + 5*MB4);
    float* omega = (float*)(wsb + YSEQ_BYTES + 6*MB4);
    float* alpha = (float*)(wsb + YSEQ_BYTES + 7*MB4);
    float* hy_t3 = (float*)(wsb + YSEQ_BYTES + 8*MB4);
    float* hy0   = (float*)(wsb + YSEQ_BYTES + 9*MB4);

    __hip_bfloat16* wt1 = (__hip_bfloat16*)(wsb + 0);          // 212,992 B
    __hip_bfloat16* wt2 = (__hip_bfloat16*)(wsb + 212992);     // 131,072 B
    __hip_bfloat16* wt3 = (__hip_bfloat16*)(wsb + 344064);     // 131,072 B

    // encoders: 3 chains fused per layer
    convf_kernel<1,0><<<dim3(4,B_,3), 1024, 0, stream>>>(
        x, x, x, om_w1, al_w1, hy_w1, om_b1, al_b1, hy_b1, om_t1, al_t1, hy_t1);
    convf_kernel<16,0><<<dim3(4,B_,3), 1024, 0, stream>>>(
        om_t1, al_t1, hy_t1, om_w2, al_w2, hy_w2, om_b2, al_b2, hy_b2, om_t2, al_t2, hy_t2);
    convf_kernel<16,0><<<dim3(4,B_,3), 1024, 0, stream>>>(
        om_t2, al_t2, hy_t2, om_w3, al_w3, hy_w3, om_b3, al_b3, hy_b3, omega, alpha, hy_t3);
    convf_kernel<16,1><<<dim3(4,B_,1), 1024, 0, stream>>>(
        hy_t3, hy_t3, hy_t3, hy_w4, hy_w4, hy_w4, hy_b4, hy_b4, hy_b4, hy0, hy0, hy0);
    // 50-step ODE (fp16 yseq out)
    ode_kernel<<<256, 1024, 0, stream>>>(omega, alpha, hy0, wy, yseq);
    // MFMA DFT: rfft magnitude -> row-major bf16 features
    dft_mfma_kernel<<<4096, 256, 0, stream>>>(yseq, fbuf);
    // weight transposes (yseq dead; wt at workspace base)
    prep_wt_kernel<<<256, 256, 0, stream>>>(ro_w1, wt1, F_,   HID_);
    prep_wt_kernel<<<256, 256, 0, stream>>>(ro_w2, wt2, HID_, HID_);
    prep_wt_kernel<<<256, 256, 0, stream>>>(ro_w3, wt3, HID_, HID_);
    // fused readout MLP (3 GEMMs + final layer + transpose in one kernel)
    mlp_fused_kernel<<<256, 512, 0, stream>>>(
        fbuf, wt1, wt2, wt3, ro_b1, ro_b2, ro_b3, ro_w4, ro_b4, out);
}

// Round 8
// 379.258 us; speedup vs baseline: 16.1283x; 1.0915x over previous
//
#include <hip/hip_runtime.h>
#include <hip/hip_bf16.h>
#include <hip/hip_fp16.h>
#include <math.h>

#define B_   16
#define C_   16
#define S_   64
#define HW_  4096
#define T_   50
#define K_   26
#define F_   416   // C_*K_
#define HID_ 256
#define NC_  7
#define DT_  0.5f
#define BCHW_ (B_*C_*HW_)
#define M_   (B_*HW_)   // 65536 rows into the MLP

typedef _Float16 f16x8  __attribute__((ext_vector_type(8)));
typedef float    f32x4  __attribute__((ext_vector_type(4)));

__device__ __forceinline__ void gld_lds16(const void* g, void* l){
    __builtin_amdgcn_global_load_lds(
        (const __attribute__((address_space(1))) void*)g,
        (__attribute__((address_space(3))) void*)l, 16, 0, 0);
}

__device__ __forceinline__ float fast_tanh(float x){
    float ax = fabsf(x);
    float e  = __expf(2.f*ax);
    float r  = 1.f - 2.f/(e + 1.f);
    return copysignf(r, x);
}

__device__ __forceinline__ short f2h_s(float f){
    __half h = __float2half(f);
    return *(short*)&h;
}

// ---------------------------------------------------------------------------
// Fused multi-chain 3x3 conv, zero 'SAME' padding. 8-row slices, 512 threads
// (42 KB LDS at CIN=16 -> 3 blocks/CU). Block = (slice, batch, chain).
// ---------------------------------------------------------------------------
template<int CIN, int ACT>
__global__ __launch_bounds__(512) void convf_kernel(
    const float* __restrict__ in0, const float* __restrict__ in1, const float* __restrict__ in2,
    const float* __restrict__ w0,  const float* __restrict__ w1,  const float* __restrict__ w2,
    const float* __restrict__ b0,  const float* __restrict__ b1,  const float* __restrict__ b2,
    float* __restrict__ o0, float* __restrict__ o1, float* __restrict__ o2)
{
    __shared__ __align__(16) float slab[CIN][10][66];
    const int slice = blockIdx.x;        // 0..7 -> rows 8*slice..8*slice+7
    const int b     = blockIdx.y;
    const int ch    = blockIdx.z;
    const float* in = (ch == 0) ? in0 : (ch == 1) ? in1 : in2;
    const float* w  = (ch == 0) ? w0  : (ch == 1) ? w1  : w2;
    const float* bb = (ch == 0) ? b0  : (ch == 1) ? b1  : b2;
    float* out      = (ch == 0) ? o0  : (ch == 1) ? o1  : o2;

    const int tid = threadIdx.x;
    const int y0  = slice * 8;

    for (int idx = tid; idx < CIN*10*66; idx += 512){
        int ci  = idx / (10*66);
        int rem = idx % (10*66);
        int rr  = rem / 66;
        int cc  = rem % 66;
        int gy = y0 - 1 + rr;
        int gx = cc - 1;
        float v = 0.f;
        if ((unsigned)gy < 64u && (unsigned)gx < 64u)
            v = in[(size_t)(b*CIN + ci)*HW_ + gy*64 + gx];
        slab[ci][rr][cc] = v;
    }
    __syncthreads();

    const int x  = tid & 63;
    const int ry = tid >> 6;             // 0..7

    float acc[16];
    #pragma unroll
    for (int co = 0; co < 16; co++) acc[co] = bb[co];

    for (int ci = 0; ci < CIN; ci++){
        float p[3][3];
        #pragma unroll
        for (int dy = 0; dy < 3; dy++)
            #pragma unroll
            for (int dx = 0; dx < 3; dx++)
                p[dy][dx] = slab[ci][ry + dy][x + dx];
        #pragma unroll
        for (int co = 0; co < 16; co++){
            const float* wp = w + (size_t)(co*CIN + ci)*9;
            float s = acc[co];
            #pragma unroll
            for (int dy = 0; dy < 3; dy++)
                #pragma unroll
                for (int dx = 0; dx < 3; dx++)
                    s = fmaf(wp[dy*3 + dx], p[dy][dx], s);
            acc[co] = s;
        }
    }
    #pragma unroll
    for (int co = 0; co < 16; co++){
        float v = acc[co];
        v = ACT ? fast_tanh(v) : fmaxf(v, 0.f);
        out[(size_t)(b*16 + co)*HW_ + (y0 + ry)*64 + x] = v;
    }
}

// ---------------------------------------------------------------------------
// 50-step coRNN ODE (unchanged from round 7). Output yseq fp16 [t][bc][hw].
// ---------------------------------------------------------------------------
__global__ __launch_bounds__(1024) void ode_kernel(
    const float* __restrict__ omega, const float* __restrict__ alpha,
    const float* __restrict__ hy0,   const float* __restrict__ wy,
    __half* __restrict__ yseq)
{
    __shared__ __align__(16) float buf[2][64*65];
    const int blk = blockIdx.x;            // b*16 + c
    const int c   = blk & 15;
    const int tid = threadIdx.x;
    const int x   = tid & 63;
    const int sy  = (tid >> 6) << 2;       // 0,4,...,60
    const size_t off = (size_t)blk * HW_;

    float om[4], al[4], hz[4], hy[4];
    #pragma unroll
    for (int i = 0; i < 4; i++){
        size_t g = off + (size_t)(sy + i)*64 + x;
        om[i] = omega[g];
        al[i] = alpha[g];
        hz[i] = 0.f;
        hy[i] = hy0[g];
        buf[0][x*65 + sy + i] = hy[i];
    }
    float wv[9];
    const float* wp = wy + (size_t)(c*C_ + c)*9;
    #pragma unroll
    for (int j = 0; j < 9; j++) wv[j] = wp[j];
    const bool five = (wv[0]==0.f) & (wv[2]==0.f) & (wv[6]==0.f) & (wv[8]==0.f);
    __syncthreads();

    const int xl = ((x + 63) & 63) * 65;
    const int xr = ((x + 1)  & 63) * 65;
    const int xo = x * 65;
    const int ylo = (sy + 63) & 63;
    const int yhi = (sy + 4)  & 63;

    int cur = 0;
    for (int t = 0; t < T_; t++){
        const float* hp = buf[cur];
        float* hn = buf[cur ^ 1];
        float l[6], r[6];
        #pragma unroll
        for (int i = 0; i < 4; i++){ l[i+1] = hp[xl + sy + i]; r[i+1] = hp[xr + sy + i]; }
        if (!five){
            l[0] = hp[xl + ylo];  r[0] = hp[xr + ylo];
            l[5] = hp[xl + yhi];  r[5] = hp[xr + yhi];
        }
        float tN = hp[xo + ylo];
        float tS = hp[xo + yhi];

        __half* yout = yseq + (size_t)t*BCHW_ + off;
        float ny[4];
        #pragma unroll
        for (int i = 0; i < 4; i++){
            float up = (i == 0) ? tN : hy[i-1];
            float dn = (i == 3) ? tS : hy[i+1];
            float s = wv[1]*up + wv[3]*l[i+1] + wv[4]*hy[i] + wv[5]*r[i+1] + wv[7]*dn;
            if (!five)
                s += wv[0]*l[i] + wv[2]*r[i] + wv[6]*l[i+2] + wv[8]*r[i+2];
            float sf = fast_tanh(s);
            float nz = hz[i] + DT_*(sf - om[i]*hy[i] - al[i]*hz[i]);
            float v  = hy[i] + DT_*nz;
            hz[i] = nz;
            ny[i] = v;
        }
        #pragma unroll
        for (int i = 0; i < 4; i++){
            hy[i] = ny[i];
            hn[xo + sy + i] = ny[i];
            yout[(sy + i)*64 + x] = __float2half(ny[i]);
        }
        __syncthreads();
        cur ^= 1;
    }
}

// ---------------------------------------------------------------------------
// MFMA DFT. __sinf/__cosf basis (HW transcendentals), fp16 in/out.
// Writes f[(b*HW+hw)*416 + c*26 + k] (fp16).
// ---------------------------------------------------------------------------
__global__ __launch_bounds__(256) void dft_mfma_kernel(
    const __half* __restrict__ yseq, __half* __restrict__ f)
{
    __shared__ __align__(16) char Ys[8*256*16];
    __shared__ __align__(16) char Gs[8*64*16];
    const int tid = threadIdx.x;
    const int blk = blockIdx.x;
    const int bc  = blk >> 4;
    const int p0  = (blk & 15) << 8;
    const int b   = bc >> 4, c = bc & 15;

    for (int idx = tid; idx < 64*64; idx += 256){
        int r = idx >> 6, t = idx & 63;
        float v = 0.f;
        if (r < 52 && t < 50){
            int k  = r >> 1;
            int ph = (k * t) % 50;
            float ang = (float)ph * (6.2831853071795864f / 50.f);
            v = (r & 1) ? __sinf(ang) : __cosf(ang);
        }
        *(_Float16*)(Gs + ((t >> 3)*64 + r)*16 + (t & 7)*2) = (_Float16)v;
    }

    {
        const __half* src = yseq + (size_t)bc*HW_ + p0 + tid;
        #pragma unroll
        for (int t2 = 0; t2 < 25; t2++){
            unsigned int a = *(const unsigned short*)&src[(size_t)(2*t2)*BCHW_];
            unsigned int d = *(const unsigned short*)&src[(size_t)(2*t2+1)*BCHW_];
            int t8 = t2 >> 2, j = t2 & 3;
            *(unsigned int*)(Ys + (t8*256 + tid)*16 + j*4) = a | (d << 16);
        }
        #pragma unroll
        for (int t2 = 25; t2 < 32; t2++){
            int t8 = t2 >> 2, j = t2 & 3;
            *(unsigned int*)(Ys + (t8*256 + tid)*16 + j*4) = 0u;
        }
    }
    __syncthreads();

    const int lane = tid & 63;
    const int w    = tid >> 6;
    const int n    = lane & 15;
    const int quad = lane >> 4;
    const int mrow = 16*w + n;

    f16x8 a0 = *(const f16x8*)(Gs + ((quad    )*64 + mrow)*16);
    f16x8 a1 = *(const f16x8*)(Gs + ((quad + 4)*64 + mrow)*16);

    const int kb0   = 8*w + 2*quad;
    const bool valid = (kb0 < K_);

    for (int nt = 0; nt < 16; nt++){
        f16x8 b0 = *(const f16x8*)(Ys + ((quad    )*256 + nt*16 + n)*16);
        f16x8 b1 = *(const f16x8*)(Ys + ((quad + 4)*256 + nt*16 + n)*16);
        f32x4 acc = (f32x4){0.f, 0.f, 0.f, 0.f};
        acc = __builtin_amdgcn_mfma_f32_16x16x32_f16(a0, b0, acc, 0, 0, 0);
        acc = __builtin_amdgcn_mfma_f32_16x16x32_f16(a1, b1, acc, 0, 0, 0);
        if (valid){
            float m0 = sqrtf(fmaf(acc[0], acc[0], acc[1]*acc[1]));
            float m1 = sqrtf(fmaf(acc[2], acc[2], acc[3]*acc[3]));
            unsigned int u = ((unsigned int)(unsigned short)f2h_s(m1) << 16)
                           |  (unsigned int)(unsigned short)f2h_s(m0);
            const int row = b*HW_ + p0 + nt*16 + n;
            *(unsigned int*)((char*)(f + (size_t)row*F_ + c*K_) + kb0*2) = u;
        }
    }
}

// ---------------------------------------------------------------------------
// One merged prep kernel: wt1 [256][416], wt2/wt3 [256][256], all fp16.
// ---------------------------------------------------------------------------
__global__ __launch_bounds__(256) void prep_all_kernel(
    const float* __restrict__ w1, const float* __restrict__ w2,
    const float* __restrict__ w3,
    __half* __restrict__ wt1, __half* __restrict__ wt2, __half* __restrict__ wt3)
{
    const int blk = blockIdx.x;
    const int tid = threadIdx.x;
    if (blk < 256){
        const int n = blk;
        for (int k = tid; k < F_; k += 256)
            wt1[(size_t)n*F_ + k] = __float2half(w1[(size_t)k*HID_ + n]);
    } else if (blk < 512){
        const int n = blk - 256;
        for (int k = tid; k < HID_; k += 256)
            wt2[(size_t)n*HID_ + k] = __float2half(w2[(size_t)k*HID_ + n]);
    } else {
        const int n = blk - 512;
        for (int k = tid; k < HID_; k += 256)
            wt3[(size_t)n*HID_ + k] = __float2half(w3[(size_t)k*HID_ + n]);
    }
}

// ---------------------------------------------------------------------------
// FUSED MLP (fp16 MFMA): relu(relu(relu(A@W1+b1)@W2+b2)@W3+b3)@W4+b4 -> NCHW.
// 512 threads = 8 waves (4m x 2n of 64x128). hbuf stride 264 shorts (528 B,
// 16B-aligned rows -> clean ds_read_b128). Bs sections padded +32 B. Final
// 256->7 layer is an MFMA with w4 staged as fp16 B-fragments (N padded to 16).
// ---------------------------------------------------------------------------
__global__ __launch_bounds__(512, 2) void mlp_fused_kernel(
    const __half* __restrict__ A,     // fbuf [M][416]
    const __half* __restrict__ Wt1,   // [256][416]
    const __half* __restrict__ Wt2,   // [256][256]
    const __half* __restrict__ Wt3,   // [256][256]
    const float* __restrict__ b1, const float* __restrict__ b2,
    const float* __restrict__ b3,
    const float* __restrict__ w4, const float* __restrict__ b4,
    float* __restrict__ out)
{
    __shared__ __align__(16) short hbuf[256*264];   // 135,168 B
    __shared__ __align__(16) short Bs[4*2064];      //  16,512 B (4128 B/section)
    __shared__ __align__(16) short Bs4[512*8];      //   8,192 B (w4 fragments)

    const int tid  = threadIdx.x;
    const int lane = tid & 63;
    const int wave = tid >> 6;
    const int wm   = (wave & 3) * 64;
    const int wn   = (wave >> 2) * 128;
    const int n16  = lane & 15;
    const int quad = lane >> 4;
    const int m0   = blockIdx.x * 256;

    // build w4 fragment table: chunk c -> (ktq = c>>4 : k = ktq*8+e, n = c&15)
    {
        const int ktq = tid >> 4, n = tid & 15;
        short vals[8];
        #pragma unroll
        for (int e = 0; e < 8; e++){
            const int k = ktq*8 + e;
            vals[e] = f2h_s((n < NC_) ? w4[(size_t)k*NC_ + n] : 0.f);
        }
        #pragma unroll
        for (int e = 0; e < 8; e++) Bs4[tid*8 + e] = vals[e];
    }

    // staging ids: chunk id -> (kc = id>>8, n = id&255)
    const int id0 = tid, id1 = tid + 512;
    const int kc0 = id0 >> 8, nn0 = id0 & 255;
    const int kc1 = id1 >> 8, nn1 = id1 & 255;
    char* dst0 = (char*)Bs + kc0*4128 + nn0*16;
    char* dst1 = (char*)Bs + kc1*4128 + nn1*16;

    f32x4 acc[4][8];
    #pragma unroll
    for (int i = 0; i < 4; i++)
        #pragma unroll
        for (int j = 0; j < 8; j++)
            acc[i][j] = (f32x4){0.f,0.f,0.f,0.f};

    // ---------------- layer 1: A from global ----------------
    const __half* arow[4];
    #pragma unroll
    for (int i = 0; i < 4; i++)
        arow[i] = A + (size_t)(m0 + wm + i*16 + n16)*F_ + quad*8;

    f16x8 afn[4];
    #pragma unroll
    for (int i = 0; i < 4; i++) afn[i] = *(const f16x8*)(arow[i]);

    for (int k0 = 0; k0 < F_; k0 += 32){
        gld_lds16(Wt1 + (size_t)nn0*F_ + k0 + kc0*8, dst0);
        gld_lds16(Wt1 + (size_t)nn1*F_ + k0 + kc1*8, dst1);
        __syncthreads();
        f16x8 af[4];
        #pragma unroll
        for (int i = 0; i < 4; i++) af[i] = afn[i];
        if (k0 + 32 < F_){
            #pragma unroll
            for (int i = 0; i < 4; i++) afn[i] = *(const f16x8*)(arow[i] + k0 + 32);
        }
        f16x8 bf[8];
        #pragma unroll
        for (int j = 0; j < 8; j++)
            bf[j] = *(const f16x8*)((char*)Bs + quad*4128 + (wn + j*16 + n16)*16);
        #pragma unroll
        for (int i = 0; i < 4; i++)
            #pragma unroll
            for (int j = 0; j < 8; j++)
                acc[i][j] = __builtin_amdgcn_mfma_f32_16x16x32_f16(
                                af[i], bf[j], acc[i][j], 0, 0, 0);
        __syncthreads();
    }
    #pragma unroll
    for (int j = 0; j < 8; j++){
        const int col = wn + j*16 + n16;
        const float bv = b1[col];
        #pragma unroll
        for (int i = 0; i < 4; i++){
            const int r0 = wm + i*16 + quad*4;
            #pragma unroll
            for (int r = 0; r < 4; r++)
                hbuf[(r0 + r)*264 + col] = f2h_s(fmaxf(acc[i][j][r] + bv, 0.f));
        }
    }
    __syncthreads();

    // ---------------- layers 2,3: A from hbuf ----------------
    const __half* Wts[2] = {Wt2, Wt3};
    const float* bls[2] = {b2, b3};
    for (int L = 0; L < 2; L++){
        const __half* Wt = Wts[L];
        #pragma unroll
        for (int i = 0; i < 4; i++)
            #pragma unroll
            for (int j = 0; j < 8; j++)
                acc[i][j] = (f32x4){0.f,0.f,0.f,0.f};

        for (int k0 = 0; k0 < HID_; k0 += 32){
            gld_lds16(Wt + (size_t)nn0*HID_ + k0 + kc0*8, dst0);
            gld_lds16(Wt + (size_t)nn1*HID_ + k0 + kc1*8, dst1);
            f16x8 af[4];
            #pragma unroll
            for (int i = 0; i < 4; i++)
                af[i] = *(const f16x8*)&hbuf[(wm + i*16 + n16)*264 + k0 + quad*8];
            __syncthreads();
            f16x8 bf[8];
            #pragma unroll
            for (int j = 0; j < 8; j++)
                bf[j] = *(const f16x8*)((char*)Bs + quad*4128 + (wn + j*16 + n16)*16);
            #pragma unroll
            for (int i = 0; i < 4; i++)
                #pragma unroll
                for (int j = 0; j < 8; j++)
                    acc[i][j] = __builtin_amdgcn_mfma_f32_16x16x32_f16(
                                    af[i], bf[j], acc[i][j], 0, 0, 0);
            __syncthreads();
        }
        const float* bl = bls[L];
        #pragma unroll
        for (int j = 0; j < 8; j++){
            const int col = wn + j*16 + n16;
            const float bv = bl[col];
            #pragma unroll
            for (int i = 0; i < 4; i++){
                const int r0 = wm + i*16 + quad*4;
                #pragma unroll
                for (int r = 0; r < 4; r++)
                    hbuf[(r0 + r)*264 + col] = f2h_s(fmaxf(acc[i][j][r] + bv, 0.f));
            }
        }
        __syncthreads();
    }

    // ---------------- final layer 256 -> 7 as MFMA + NCHW transpose --------
    // wave w handles rows w*32..w*32+31 (2 m-tiles of 16). N padded 7->16.
    f32x4 facc[2] = {(f32x4){0.f,0.f,0.f,0.f}, (f32x4){0.f,0.f,0.f,0.f}};
    #pragma unroll
    for (int kt = 0; kt < 8; kt++){
        f16x8 bfr = *(const f16x8*)&Bs4[((kt*4 + quad)*16 + n16)*8];
        #pragma unroll
        for (int mt = 0; mt < 2; mt++){
            f16x8 af = *(const f16x8*)&hbuf[(wave*32 + mt*16 + n16)*264 + kt*32 + quad*8];
            facc[mt] = __builtin_amdgcn_mfma_f32_16x16x32_f16(af, bfr, facc[mt], 0, 0, 0);
        }
    }
    if (n16 < NC_){
        const float bv = b4[n16];
        #pragma unroll
        for (int mt = 0; mt < 2; mt++){
            #pragma unroll
            for (int r = 0; r < 4; r++){
                const int grow = m0 + wave*32 + mt*16 + quad*4 + r;
                const int bidx = grow >> 12, hw = grow & 4095;
                out[(size_t)(bidx*NC_ + n16)*HW_ + hw] = facc[mt][r] + bv;
            }
        }
    }
}

// ---------------------------------------------------------------------------
// Workspace (peak 159,383,552 B, proven):
//   yseq fp16 [50][256][4096] @ 0 (104,857,600)         ODE w, DFT r
//   fbuf fp16 [65536][416] @ 104,857,600 (54,525,952)   DFT w, MLP r
//     conv temps (10 x 4 MiB) aliased in fbuf region (dead before DFT)
//   wt1/2/3 fp16 @ 0 (yseq region, dead after DFT)
// ---------------------------------------------------------------------------
extern "C" void kernel_launch(void* const* d_in, const int* in_sizes, int n_in,
                              void* d_out, int out_size, void* d_ws, size_t ws_size,
                              hipStream_t stream)
{
    const float* x     = (const float*)d_in[0];
    const float* om_w1 = (const float*)d_in[1];  const float* om_b1 = (const float*)d_in[2];
    const float* om_w2 = (const float*)d_in[3];  const float* om_b2 = (const float*)d_in[4];
    const float* om_w3 = (const float*)d_in[5];  const float* om_b3 = (const float*)d_in[6];
    const float* al_w1 = (const float*)d_in[7];  const float* al_b1 = (const float*)d_in[8];
    const float* al_w2 = (const float*)d_in[9];  const float* al_b2 = (const float*)d_in[10];
    const float* al_w3 = (const float*)d_in[11]; const float* al_b3 = (const float*)d_in[12];
    const float* hy_w1 = (const float*)d_in[13]; const float* hy_b1 = (const float*)d_in[14];
    const float* hy_w2 = (const float*)d_in[15]; const float* hy_b2 = (const float*)d_in[16];
    const float* hy_w3 = (const float*)d_in[17]; const float* hy_b3 = (const float*)d_in[18];
    const float* hy_w4 = (const float*)d_in[19]; const float* hy_b4 = (const float*)d_in[20];
    const float* wy    = (const float*)d_in[21];
    const float* ro_w1 = (const float*)d_in[22]; const float* ro_b1 = (const float*)d_in[23];
    const float* ro_w2 = (const float*)d_in[24]; const float* ro_b2 = (const float*)d_in[25];
    const float* ro_w3 = (const float*)d_in[26]; const float* ro_b3 = (const float*)d_in[27];
    const float* ro_w4 = (const float*)d_in[28]; const float* ro_b4 = (const float*)d_in[29];
    float* out = (float*)d_out;

    char* wsb = (char*)d_ws;
    const size_t YSEQ_BYTES = (size_t)T_ * BCHW_ * 2;          // 104,857,600
    __half* yseq = (__half*)wsb;
    __half* fbuf = (__half*)(wsb + YSEQ_BYTES);

    const size_t MB4 = (size_t)BCHW_ * 4;                      // 4 MiB
    float* om_t1 = (float*)(wsb + YSEQ_BYTES + 0*MB4);
    float* al_t1 = (float*)(wsb + YSEQ_BYTES + 1*MB4);
    float* hy_t1 = (float*)(wsb + YSEQ_BYTES + 2*MB4);
    float* om_t2 = (float*)(wsb + YSEQ_BYTES + 3*MB4);
    float* al_t2 = (float*)(wsb + YSEQ_BYTES + 4*MB4);
    float* hy_t2 = (float*)(wsb + YSEQ_BYTES + 5*MB4);
    float* omega = (float*)(wsb + YSEQ_BYTES + 6*MB4);
    float* alpha = (float*)(wsb + YSEQ_BYTES + 7*MB4);
    float* hy_t3 = (float*)(wsb + YSEQ_BYTES + 8*MB4);
    float* hy0   = (float*)(wsb + YSEQ_BYTES + 9*MB4);

    __half* wt1 = (__half*)(wsb + 0);          // 212,992 B
    __half* wt2 = (__half*)(wsb + 212992);     // 131,072 B
    __half* wt3 = (__half*)(wsb + 344064);     // 131,072 B

    // encoders: 3 chains fused per layer, 8-row slices
    convf_kernel<1,0><<<dim3(8,B_,3), 512, 0, stream>>>(
        x, x, x, om_w1, al_w1, hy_w1, om_b1, al_b1, hy_b1, om_t1, al_t1, hy_t1);
    convf_kernel<16,0><<<dim3(8,B_,3), 512, 0, stream>>>(
        om_t1, al_t1, hy_t1, om_w2, al_w2, hy_w2, om_b2, al_b2, hy_b2, om_t2, al_t2, hy_t2);
    convf_kernel<16,0><<<dim3(8,B_,3), 512, 0, stream>>>(
        om_t2, al_t2, hy_t2, om_w3, al_w3, hy_w3, om_b3, al_b3, hy_b3, omega, alpha, hy_t3);
    convf_kernel<16,1><<<dim3(8,B_,1), 512, 0, stream>>>(
        hy_t3, hy_t3, hy_t3, hy_w4, hy_w4, hy_w4, hy_b4, hy_b4, hy_b4, hy0, hy0, hy0);
    // 50-step ODE (fp16 yseq out)
    ode_kernel<<<256, 1024, 0, stream>>>(omega, alpha, hy0, wy, yseq);
    // MFMA DFT: rfft magnitude -> row-major fp16 features
    dft_mfma_kernel<<<4096, 256, 0, stream>>>(yseq, fbuf);
    // merged weight transposes (yseq dead; wt at workspace base)
    prep_all_kernel<<<768, 256, 0, stream>>>(ro_w1, ro_w2, ro_w3, wt1, wt2, wt3);
    // fused readout MLP (3 GEMMs + MFMA final layer + transpose)
    mlp_fused_kernel<<<256, 512, 0, stream>>>(
        fbuf, wt1, wt2, wt3, ro_b1, ro_b2, ro_b3, ro_w4, ro_b4, out);
}

// Round 10
// 376.077 us; speedup vs baseline: 16.2648x; 1.0085x over previous
//
#include <hip/hip_runtime.h>
#include <hip/hip_bf16.h>
#include <hip/hip_fp16.h>
#include <math.h>

#define B_   16
#define C_   16
#define S_   64
#define HW_  4096
#define T_   50
#define K_   26
#define F_   416   // C_*K_
#define HID_ 256
#define NC_  7
#define DT_  0.5f
#define BCHW_ (B_*C_*HW_)
#define M_   (B_*HW_)   // 65536 rows into the MLP

typedef _Float16 f16x8  __attribute__((ext_vector_type(8)));
typedef __fp16   fp16x2 __attribute__((ext_vector_type(2)));
typedef float    f32x4  __attribute__((ext_vector_type(4)));

__device__ __forceinline__ void gld_lds16(const void* g, void* l){
    __builtin_amdgcn_global_load_lds(
        (const __attribute__((address_space(1))) void*)g,
        (__attribute__((address_space(3))) void*)l, 16, 0, 0);
}

__device__ __forceinline__ float fast_tanh(float x){
    float ax = fabsf(x);
    float e  = __expf(2.f*ax);
    float r  = 1.f - 2.f/(e + 1.f);
    return copysignf(r, x);
}

__device__ __forceinline__ short f2h_s(float f){
    __half h = __float2half(f);
    return *(short*)&h;
}

// ---------------------------------------------------------------------------
// Fused multi-chain 3x3 conv, zero 'SAME' padding. (unchanged from round 8)
// ---------------------------------------------------------------------------
template<int CIN, int ACT>
__global__ __launch_bounds__(512) void convf_kernel(
    const float* __restrict__ in0, const float* __restrict__ in1, const float* __restrict__ in2,
    const float* __restrict__ w0,  const float* __restrict__ w1,  const float* __restrict__ w2,
    const float* __restrict__ b0,  const float* __restrict__ b1,  const float* __restrict__ b2,
    float* __restrict__ o0, float* __restrict__ o1, float* __restrict__ o2)
{
    __shared__ __align__(16) float slab[CIN][10][66];
    const int slice = blockIdx.x;
    const int b     = blockIdx.y;
    const int ch    = blockIdx.z;
    const float* in = (ch == 0) ? in0 : (ch == 1) ? in1 : in2;
    const float* w  = (ch == 0) ? w0  : (ch == 1) ? w1  : w2;
    const float* bb = (ch == 0) ? b0  : (ch == 1) ? b1  : b2;
    float* out      = (ch == 0) ? o0  : (ch == 1) ? o1  : o2;

    const int tid = threadIdx.x;
    const int y0  = slice * 8;

    for (int idx = tid; idx < CIN*10*66; idx += 512){
        int ci  = idx / (10*66);
        int rem = idx % (10*66);
        int rr  = rem / 66;
        int cc  = rem % 66;
        int gy = y0 - 1 + rr;
        int gx = cc - 1;
        float v = 0.f;
        if ((unsigned)gy < 64u && (unsigned)gx < 64u)
            v = in[(size_t)(b*CIN + ci)*HW_ + gy*64 + gx];
        slab[ci][rr][cc] = v;
    }
    __syncthreads();

    const int x  = tid & 63;
    const int ry = tid >> 6;

    float acc[16];
    #pragma unroll
    for (int co = 0; co < 16; co++) acc[co] = bb[co];

    for (int ci = 0; ci < CIN; ci++){
        float p[3][3];
        #pragma unroll
        for (int dy = 0; dy < 3; dy++)
            #pragma unroll
            for (int dx = 0; dx < 3; dx++)
                p[dy][dx] = slab[ci][ry + dy][x + dx];
        #pragma unroll
        for (int co = 0; co < 16; co++){
            const float* wp = w + (size_t)(co*CIN + ci)*9;
            float s = acc[co];
            #pragma unroll
            for (int dy = 0; dy < 3; dy++)
                #pragma unroll
                for (int dx = 0; dx < 3; dx++)
                    s = fmaf(wp[dy*3 + dx], p[dy][dx], s);
            acc[co] = s;
        }
    }
    #pragma unroll
    for (int co = 0; co < 16; co++){
        float v = acc[co];
        v = ACT ? fast_tanh(v) : fmaxf(v, 0.f);
        out[(size_t)(b*16 + co)*HW_ + (y0 + ry)*64 + x] = v;
    }
}

// ---------------------------------------------------------------------------
// 50-step coRNN ODE, row-segment ownership: thread owns 4 x-consecutive
// pixels (y fixed). LDS row-major stride 68 (16B-aligned b128 rows).
// Per step: 2 ds_read_b128 (up/dn) + 2 ds_read_b32 (l/r) + 1 ds_write_b128
// + one packed 8B global store (cvt_pkrtz). Preconditioned coefficients.
// ---------------------------------------------------------------------------
__global__ __launch_bounds__(1024) void ode_kernel(
    const float* __restrict__ omega, const float* __restrict__ alpha,
    const float* __restrict__ hy0,   const float* __restrict__ wy,
    __half* __restrict__ yseq)
{
    __shared__ __align__(16) float buf[2][64*68];
    const int blk = blockIdx.x;            // b*16 + c
    const int c   = blk & 15;
    const int tid = threadIdx.x;
    const int y   = tid >> 4;              // 0..63
    const int xq  = (tid & 15) << 2;       // 0,4,...,60
    const size_t off = (size_t)blk * HW_;
    const int g0  = y*64 + xq;

    float4 om4 = *(const float4*)(omega + off + g0);
    float4 al4 = *(const float4*)(alpha + off + g0);
    float4 h4  = *(const float4*)(hy0   + off + g0);
    float omv[4] = {om4.x, om4.y, om4.z, om4.w};
    float alv[4] = {al4.x, al4.y, al4.z, al4.w};
    float hy[4]  = {h4.x, h4.y, h4.z, h4.w};
    float hz[4]  = {0.f, 0.f, 0.f, 0.f};
    #pragma unroll
    for (int i = 0; i < 4; i++){
        omv[i] = DT_ * omv[i];            // om' = DT*om
        alv[i] = 1.f - DT_ * alv[i];      // al' = 1 - DT*al
    }
    *(float4*)&buf[0][y*68 + xq] = h4;

    float wv[9];
    const float* wp = wy + (size_t)(c*C_ + c)*9;
    #pragma unroll
    for (int j = 0; j < 9; j++) wv[j] = wp[j];
    const bool five = (wv[0]==0.f) & (wv[2]==0.f) & (wv[6]==0.f) & (wv[8]==0.f);
    __syncthreads();

    const int ym = ((y + 63) & 63) * 68;
    const int yp = ((y + 1)  & 63) * 68;
    const int yo = y * 68;
    const int xm = (xq + 63) & 63;         // x-1 wrapped
    const int xp = (xq + 4)  & 63;         // x+4 wrapped
    const __half* ybase = yseq + off + g0;

    int cur = 0;
    for (int t = 0; t < T_; t++){
        const float* hp = buf[cur];
        float* hn = buf[cur ^ 1];
        float4 up4 = *(const float4*)&hp[ym + xq];
        float4 dn4 = *(const float4*)&hp[yp + xq];
        float upv[4] = {up4.x, up4.y, up4.z, up4.w};
        float dnv[4] = {dn4.x, dn4.y, dn4.z, dn4.w};
        float lft = hp[yo + xm];
        float rgt = hp[yo + xp];

        float ny[4];
        if (five){
            #pragma unroll
            for (int i = 0; i < 4; i++){
                float l = (i == 0) ? lft : hy[i-1];
                float r = (i == 3) ? rgt : hy[i+1];
                float s = wv[1]*upv[i] + wv[7]*dnv[i] + wv[3]*l + wv[5]*r + wv[4]*hy[i];
                float sf = fast_tanh(s);
                float nz = fmaf(alv[i], hz[i], fmaf(-omv[i], hy[i], DT_*sf));
                ny[i] = fmaf(DT_, nz, hy[i]);
                hz[i] = nz;
            }
        } else {
            float ul = hp[ym + xm], ur = hp[ym + xp];
            float dl = hp[yp + xm], dr = hp[yp + xp];
            #pragma unroll
            for (int i = 0; i < 4; i++){
                float l  = (i == 0) ? lft : hy[i-1];
                float r  = (i == 3) ? rgt : hy[i+1];
                float uL = (i == 0) ? ul  : upv[i-1];
                float uR = (i == 3) ? ur  : upv[i+1];
                float dL = (i == 0) ? dl  : dnv[i-1];
                float dR = (i == 3) ? dr  : dnv[i+1];
                float s = wv[0]*uL + wv[1]*upv[i] + wv[2]*uR
                        + wv[3]*l  + wv[4]*hy[i]  + wv[5]*r
                        + wv[6]*dL + wv[7]*dnv[i] + wv[8]*dR;
                float sf = fast_tanh(s);
                float nz = fmaf(alv[i], hz[i], fmaf(-omv[i], hy[i], DT_*sf));
                ny[i] = fmaf(DT_, nz, hy[i]);
                hz[i] = nz;
            }
        }
        #pragma unroll
        for (int i = 0; i < 4; i++) hy[i] = ny[i];
        *(float4*)&hn[yo + xq] = make_float4(ny[0], ny[1], ny[2], ny[3]);

        union { fp16x2 h2[2]; uint2 u; } pk;
        pk.h2[0] = __builtin_amdgcn_cvt_pkrtz(ny[0], ny[1]);
        pk.h2[1] = __builtin_amdgcn_cvt_pkrtz(ny[2], ny[3]);
        *(uint2*)(ybase + (size_t)t*BCHW_) = pk.u;

        __syncthreads();
        cur ^= 1;
    }
}

// ---------------------------------------------------------------------------
// MFMA DFT (unchanged from round 8). fp16 in/out.
// ---------------------------------------------------------------------------
__global__ __launch_bounds__(256) void dft_mfma_kernel(
    const __half* __restrict__ yseq, __half* __restrict__ f)
{
    __shared__ __align__(16) char Ys[8*256*16];
    __shared__ __align__(16) char Gs[8*64*16];
    const int tid = threadIdx.x;
    const int blk = blockIdx.x;
    const int bc  = blk >> 4;
    const int p0  = (blk & 15) << 8;
    const int b   = bc >> 4, c = bc & 15;

    for (int idx = tid; idx < 64*64; idx += 256){
        int r = idx >> 6, t = idx & 63;
        float v = 0.f;
        if (r < 52 && t < 50){
            int k  = r >> 1;
            int ph = (k * t) % 50;
            float ang = (float)ph * (6.2831853071795864f / 50.f);
            v = (r & 1) ? __sinf(ang) : __cosf(ang);
        }
        *(_Float16*)(Gs + ((t >> 3)*64 + r)*16 + (t & 7)*2) = (_Float16)v;
    }

    {
        const __half* src = yseq + (size_t)bc*HW_ + p0 + tid;
        #pragma unroll
        for (int t2 = 0; t2 < 25; t2++){
            unsigned int a = *(const unsigned short*)&src[(size_t)(2*t2)*BCHW_];
            unsigned int d = *(const unsigned short*)&src[(size_t)(2*t2+1)*BCHW_];
            int t8 = t2 >> 2, j = t2 & 3;
            *(unsigned int*)(Ys + (t8*256 + tid)*16 + j*4) = a | (d << 16);
        }
        #pragma unroll
        for (int t2 = 25; t2 < 32; t2++){
            int t8 = t2 >> 2, j = t2 & 3;
            *(unsigned int*)(Ys + (t8*256 + tid)*16 + j*4) = 0u;
        }
    }
    __syncthreads();

    const int lane = tid & 63;
    const int w    = tid >> 6;
    const int n    = lane & 15;
    const int quad = lane >> 4;
    const int mrow = 16*w + n;

    f16x8 a0 = *(const f16x8*)(Gs + ((quad    )*64 + mrow)*16);
    f16x8 a1 = *(const f16x8*)(Gs + ((quad + 4)*64 + mrow)*16);

    const int kb0   = 8*w + 2*quad;
    const bool valid = (kb0 < K_);

    for (int nt = 0; nt < 16; nt++){
        f16x8 b0 = *(const f16x8*)(Ys + ((quad    )*256 + nt*16 + n)*16);
        f16x8 b1 = *(const f16x8*)(Ys + ((quad + 4)*256 + nt*16 + n)*16);
        f32x4 acc = (f32x4){0.f, 0.f, 0.f, 0.f};
        acc = __builtin_amdgcn_mfma_f32_16x16x32_f16(a0, b0, acc, 0, 0, 0);
        acc = __builtin_amdgcn_mfma_f32_16x16x32_f16(a1, b1, acc, 0, 0, 0);
        if (valid){
            float m0 = sqrtf(fmaf(acc[0], acc[0], acc[1]*acc[1]));
            float m1 = sqrtf(fmaf(acc[2], acc[2], acc[3]*acc[3]));
            unsigned int u = ((unsigned int)(unsigned short)f2h_s(m1) << 16)
                           |  (unsigned int)(unsigned short)f2h_s(m0);
            const int row = b*HW_ + p0 + nt*16 + n;
            *(unsigned int*)((char*)(f + (size_t)row*F_ + c*K_) + kb0*2) = u;
        }
    }
}

// ---------------------------------------------------------------------------
// One merged prep kernel: wt1 [256][416], wt2/wt3 [256][256], all fp16.
// ---------------------------------------------------------------------------
__global__ __launch_bounds__(256) void prep_all_kernel(
    const float* __restrict__ w1, const float* __restrict__ w2,
    const float* __restrict__ w3,
    __half* __restrict__ wt1, __half* __restrict__ wt2, __half* __restrict__ wt3)
{
    const int blk = blockIdx.x;
    const int tid = threadIdx.x;
    if (blk < 256){
        const int n = blk;
        for (int k = tid; k < F_; k += 256)
            wt1[(size_t)n*F_ + k] = __float2half(w1[(size_t)k*HID_ + n]);
    } else if (blk < 512){
        const int n = blk - 256;
        for (int k = tid; k < HID_; k += 256)
            wt2[(size_t)n*HID_ + k] = __float2half(w2[(size_t)k*HID_ + n]);
    } else {
        const int n = blk - 512;
        for (int k = tid; k < HID_; k += 256)
            wt3[(size_t)n*HID_ + k] = __float2half(w3[(size_t)k*HID_ + n]);
    }
}

// ---------------------------------------------------------------------------
// FUSED MLP (unchanged from round 8).
// ---------------------------------------------------------------------------
__global__ __launch_bounds__(512, 2) void mlp_fused_kernel(
    const __half* __restrict__ A,     // fbuf [M][416]
    const __half* __restrict__ Wt1,   // [256][416]
    const __half* __restrict__ Wt2,   // [256][256]
    const __half* __restrict__ Wt3,   // [256][256]
    const float* __restrict__ b1, const float* __restrict__ b2,
    const float* __restrict__ b3,
    const float* __restrict__ w4, const float* __restrict__ b4,
    float* __restrict__ out)
{
    __shared__ __align__(16) short hbuf[256*264];   // 135,168 B
    __shared__ __align__(16) short Bs[4*2064];      //  16,512 B (4128 B/section)
    __shared__ __align__(16) short Bs4[512*8];      //   8,192 B (w4 fragments)

    const int tid  = threadIdx.x;
    const int lane = tid & 63;
    const int wave = tid >> 6;
    const int wm   = (wave & 3) * 64;
    const int wn   = (wave >> 2) * 128;
    const int n16  = lane & 15;
    const int quad = lane >> 4;
    const int m0   = blockIdx.x * 256;

    {
        const int ktq = tid >> 4, n = tid & 15;
        short vals[8];
        #pragma unroll
        for (int e = 0; e < 8; e++){
            const int k = ktq*8 + e;
            vals[e] = f2h_s((n < NC_) ? w4[(size_t)k*NC_ + n] : 0.f);
        }
        #pragma unroll
        for (int e = 0; e < 8; e++) Bs4[tid*8 + e] = vals[e];
    }

    const int id0 = tid, id1 = tid + 512;
    const int kc0 = id0 >> 8, nn0 = id0 & 255;
    const int kc1 = id1 >> 8, nn1 = id1 & 255;
    char* dst0 = (char*)Bs + kc0*4128 + nn0*16;
    char* dst1 = (char*)Bs + kc1*4128 + nn1*16;

    f32x4 acc[4][8];
    #pragma unroll
    for (int i = 0; i < 4; i++)
        #pragma unroll
        for (int j = 0; j < 8; j++)
            acc[i][j] = (f32x4){0.f,0.f,0.f,0.f};

    // ---------------- layer 1: A from global ----------------
    const __half* arow[4];
    #pragma unroll
    for (int i = 0; i < 4; i++)
        arow[i] = A + (size_t)(m0 + wm + i*16 + n16)*F_ + quad*8;

    f16x8 afn[4];
    #pragma unroll
    for (int i = 0; i < 4; i++) afn[i] = *(const f16x8*)(arow[i]);

    for (int k0 = 0; k0 < F_; k0 += 32){
        gld_lds16(Wt1 + (size_t)nn0*F_ + k0 + kc0*8, dst0);
        gld_lds16(Wt1 + (size_t)nn1*F_ + k0 + kc1*8, dst1);
        __syncthreads();
        f16x8 af[4];
        #pragma unroll
        for (int i = 0; i < 4; i++) af[i] = afn[i];
        if (k0 + 32 < F_){
            #pragma unroll
            for (int i = 0; i < 4; i++) afn[i] = *(const f16x8*)(arow[i] + k0 + 32);
        }
        f16x8 bf[8];
        #pragma unroll
        for (int j = 0; j < 8; j++)
            bf[j] = *(const f16x8*)((char*)Bs + quad*4128 + (wn + j*16 + n16)*16);
        #pragma unroll
        for (int i = 0; i < 4; i++)
            #pragma unroll
            for (int j = 0; j < 8; j++)
                acc[i][j] = __builtin_amdgcn_mfma_f32_16x16x32_f16(
                                af[i], bf[j], acc[i][j], 0, 0, 0);
        __syncthreads();
    }
    #pragma unroll
    for (int j = 0; j < 8; j++){
        const int col = wn + j*16 + n16;
        const float bv = b1[col];
        #pragma unroll
        for (int i = 0; i < 4; i++){
            const int r0 = wm + i*16 + quad*4;
            #pragma unroll
            for (int r = 0; r < 4; r++)
                hbuf[(r0 + r)*264 + col] = f2h_s(fmaxf(acc[i][j][r] + bv, 0.f));
        }
    }
    __syncthreads();

    // ---------------- layers 2,3: A from hbuf ----------------
    const __half* Wts[2] = {Wt2, Wt3};
    const float* bls[2] = {b2, b3};
    for (int L = 0; L < 2; L++){
        const __half* Wt = Wts[L];
        #pragma unroll
        for (int i = 0; i < 4; i++)
            #pragma unroll
            for (int j = 0; j < 8; j++)
                acc[i][j] = (f32x4){0.f,0.f,0.f,0.f};

        for (int k0 = 0; k0 < HID_; k0 += 32){
            gld_lds16(Wt + (size_t)nn0*HID_ + k0 + kc0*8, dst0);
            gld_lds16(Wt + (size_t)nn1*HID_ + k0 + kc1*8, dst1);
            f16x8 af[4];
            #pragma unroll
            for (int i = 0; i < 4; i++)
                af[i] = *(const f16x8*)&hbuf[(wm + i*16 + n16)*264 + k0 + quad*8];
            __syncthreads();
            f16x8 bf[8];
            #pragma unroll
            for (int j = 0; j < 8; j++)
                bf[j] = *(const f16x8*)((char*)Bs + quad*4128 + (wn + j*16 + n16)*16);
            #pragma unroll
            for (int i = 0; i < 4; i++)
                #pragma unroll
                for (int j = 0; j < 8; j++)
                    acc[i][j] = __builtin_amdgcn_mfma_f32_16x16x32_f16(
                                    af[i], bf[j], acc[i][j], 0, 0, 0);
            __syncthreads();
        }
        const float* bl = bls[L];
        #pragma unroll
        for (int j = 0; j < 8; j++){
            const int col = wn + j*16 + n16;
            const float bv = bl[col];
            #pragma unroll
            for (int i = 0; i < 4; i++){
                const int r0 = wm + i*16 + quad*4;
                #pragma unroll
                for (int r = 0; r < 4; r++)
                    hbuf[(r0 + r)*264 + col] = f2h_s(fmaxf(acc[i][j][r] + bv, 0.f));
            }
        }
        __syncthreads();
    }

    // ---------------- final layer 256 -> 7 as MFMA + NCHW transpose --------
    f32x4 facc[2] = {(f32x4){0.f,0.f,0.f,0.f}, (f32x4){0.f,0.f,0.f,0.f}};
    #pragma unroll
    for (int kt = 0; kt < 8; kt++){
        f16x8 bfr = *(const f16x8*)&Bs4[((kt*4 + quad)*16 + n16)*8];
        #pragma unroll
        for (int mt = 0; mt < 2; mt++){
            f16x8 af = *(const f16x8*)&hbuf[(wave*32 + mt*16 + n16)*264 + kt*32 + quad*8];
            facc[mt] = __builtin_amdgcn_mfma_f32_16x16x32_f16(af, bfr, facc[mt], 0, 0, 0);
        }
    }
    if (n16 < NC_){
        const float bv = b4[n16];
        #pragma unroll
        for (int mt = 0; mt < 2; mt++){
            #pragma unroll
            for (int r = 0; r < 4; r++){
                const int grow = m0 + wave*32 + mt*16 + quad*4 + r;
                const int bidx = grow >> 12, hw = grow & 4095;
                out[(size_t)(bidx*NC_ + n16)*HW_ + hw] = facc[mt][r] + bv;
            }
        }
    }
}

// ---------------------------------------------------------------------------
// Workspace (peak 159,383,552 B, proven):
//   yseq fp16 [50][256][4096] @ 0 (104,857,600)         ODE w, DFT r
//   fbuf fp16 [65536][416] @ 104,857,600 (54,525,952)   DFT w, MLP r
//     conv temps (10 x 4 MiB) aliased in fbuf region (dead before DFT)
//   wt1/2/3 fp16 @ 0 (yseq region, dead after DFT)
// ---------------------------------------------------------------------------
extern "C" void kernel_launch(void* const* d_in, const int* in_sizes, int n_in,
                              void* d_out, int out_size, void* d_ws, size_t ws_size,
                              hipStream_t stream)
{
    const float* x     = (const float*)d_in[0];
    const float* om_w1 = (const float*)d_in[1];  const float* om_b1 = (const float*)d_in[2];
    const float* om_w2 = (const float*)d_in[3];  const float* om_b2 = (const float*)d_in[4];
    const float* om_w3 = (const float*)d_in[5];  const float* om_b3 = (const float*)d_in[6];
    const float* al_w1 = (const float*)d_in[7];  const float* al_b1 = (const float*)d_in[8];
    const float* al_w2 = (const float*)d_in[9];  const float* al_b2 = (const float*)d_in[10];
    const float* al_w3 = (const float*)d_in[11]; const float* al_b3 = (const float*)d_in[12];
    const float* hy_w1 = (const float*)d_in[13]; const float* hy_b1 = (const float*)d_in[14];
    const float* hy_w2 = (const float*)d_in[15]; const float* hy_b2 = (const float*)d_in[16];
    const float* hy_w3 = (const float*)d_in[17]; const float* hy_b3 = (const float*)d_in[18];
    const float* hy_w4 = (const float*)d_in[19]; const float* hy_b4 = (const float*)d_in[20];
    const float* wy    = (const float*)d_in[21];
    const float* ro_w1 = (const float*)d_in[22]; const float* ro_b1 = (const float*)d_in[23];
    const float* ro_w2 = (const float*)d_in[24]; const float* ro_b2 = (const float*)d_in[25];
    const float* ro_w3 = (const float*)d_in[26]; const float* ro_b3 = (const float*)d_in[27];
    const float* ro_w4 = (const float*)d_in[28]; const float* ro_b4 = (const float*)d_in[29];
    float* out = (float*)d_out;

    char* wsb = (char*)d_ws;
    const size_t YSEQ_BYTES = (size_t)T_ * BCHW_ * 2;          // 104,857,600
    __half* yseq = (__half*)wsb;
    __half* fbuf = (__half*)(wsb + YSEQ_BYTES);

    const size_t MB4 = (size_t)BCHW_ * 4;                      // 4 MiB
    float* om_t1 = (float*)(wsb + YSEQ_BYTES + 0*MB4);
    float* al_t1 = (float*)(wsb + YSEQ_BYTES + 1*MB4);
    float* hy_t1 = (float*)(wsb + YSEQ_BYTES + 2*MB4);
    float* om_t2 = (float*)(wsb + YSEQ_BYTES + 3*MB4);
    float* al_t2 = (float*)(wsb + YSEQ_BYTES + 4*MB4);
    float* hy_t2 = (float*)(wsb + YSEQ_BYTES + 5*MB4);
    float* omega = (float*)(wsb + YSEQ_BYTES + 6*MB4);
    float* alpha = (float*)(wsb + YSEQ_BYTES + 7*MB4);
    float* hy_t3 = (float*)(wsb + YSEQ_BYTES + 8*MB4);
    float* hy0   = (float*)(wsb + YSEQ_BYTES + 9*MB4);

    __half* wt1 = (__half*)(wsb + 0);          // 212,992 B
    __half* wt2 = (__half*)(wsb + 212992);     // 131,072 B
    __half* wt3 = (__half*)(wsb + 344064);     // 131,072 B

    // encoders: 3 chains fused per layer, 8-row slices
    convf_kernel<1,0><<<dim3(8,B_,3), 512, 0, stream>>>(
        x, x, x, om_w1, al_w1, hy_w1, om_b1, al_b1, hy_b1, om_t1, al_t1, hy_t1);
    convf_kernel<16,0><<<dim3(8,B_,3), 512, 0, stream>>>(
        om_t1, al_t1, hy_t1, om_w2, al_w2, hy_w2, om_b2, al_b2, hy_b2, om_t2, al_t2, hy_t2);
    convf_kernel<16,0><<<dim3(8,B_,3), 512, 0, stream>>>(
        om_t2, al_t2, hy_t2, om_w3, al_w3, hy_w3, om_b3, al_b3, hy_b3, omega, alpha, hy_t3);
    convf_kernel<16,1><<<dim3(8,B_,1), 512, 0, stream>>>(
        hy_t3, hy_t3, hy_t3, hy_w4, hy_w4, hy_w4, hy_b4, hy_b4, hy_b4, hy0, hy0, hy0);
    // 50-step ODE (fp16 yseq out, packed stores)
    ode_kernel<<<256, 1024, 0, stream>>>(omega, alpha, hy0, wy, yseq);
    // MFMA DFT: rfft magnitude -> row-major fp16 features
    dft_mfma_kernel<<<4096, 256, 0, stream>>>(yseq, fbuf);
    // merged weight transposes (yseq dead; wt at workspace base)
    prep_all_kernel<<<768, 256, 0, stream>>>(ro_w1, ro_w2, ro_w3, wt1, wt2, wt3);
    // fused readout MLP (3 GEMMs + MFMA final layer + transpose)
    mlp_fused_kernel<<<256, 512, 0, stream>>>(
        fbuf, wt1, wt2, wt3, ro_b1, ro_b2, ro_b3, ro_w4, ro_b4, out);
}

// Round 11
// 372.488 us; speedup vs baseline: 16.4214x; 1.0096x over previous
//
#include <hip/hip_runtime.h>
#include <hip/hip_bf16.h>
#include <hip/hip_fp16.h>
#include <math.h>

#define B_   16
#define C_   16
#define S_   64
#define HW_  4096
#define T_   50
#define K_   26
#define F_   416   // C_*K_
#define HID_ 256
#define NC_  7
#define DT_  0.5f
#define BCHW_ (B_*C_*HW_)
#define M_   (B_*HW_)   // 65536 rows into the MLP

typedef _Float16 f16x8  __attribute__((ext_vector_type(8)));
typedef __fp16   fp16x2 __attribute__((ext_vector_type(2)));
typedef float    f32x4  __attribute__((ext_vector_type(4)));
typedef float    f32x2  __attribute__((ext_vector_type(2)));

__device__ __forceinline__ void gld_lds16(const void* g, void* l){
    __builtin_amdgcn_global_load_lds(
        (const __attribute__((address_space(1))) void*)g,
        (__attribute__((address_space(3))) void*)l, 16, 0, 0);
}

__device__ __forceinline__ float fast_tanh(float x){
    float ax = fabsf(x);
    float e  = __expf(2.f*ax);
    float r  = 1.f - 2.f/(e + 1.f);
    return copysignf(r, x);
}

__device__ __forceinline__ short f2h_s(float f){
    __half h = __float2half(f);
    return *(short*)&h;
}

// ---------------------------------------------------------------------------
// Fused multi-chain 3x3 conv, zero 'SAME' padding. (unchanged from round 8)
// ---------------------------------------------------------------------------
template<int CIN, int ACT>
__global__ __launch_bounds__(512) void convf_kernel(
    const float* __restrict__ in0, const float* __restrict__ in1, const float* __restrict__ in2,
    const float* __restrict__ w0,  const float* __restrict__ w1,  const float* __restrict__ w2,
    const float* __restrict__ b0,  const float* __restrict__ b1,  const float* __restrict__ b2,
    float* __restrict__ o0, float* __restrict__ o1, float* __restrict__ o2)
{
    __shared__ __align__(16) float slab[CIN][10][66];
    const int slice = blockIdx.x;
    const int b     = blockIdx.y;
    const int ch    = blockIdx.z;
    const float* in = (ch == 0) ? in0 : (ch == 1) ? in1 : in2;
    const float* w  = (ch == 0) ? w0  : (ch == 1) ? w1  : w2;
    const float* bb = (ch == 0) ? b0  : (ch == 1) ? b1  : b2;
    float* out      = (ch == 0) ? o0  : (ch == 1) ? o1  : o2;

    const int tid = threadIdx.x;
    const int y0  = slice * 8;

    for (int idx = tid; idx < CIN*10*66; idx += 512){
        int ci  = idx / (10*66);
        int rem = idx % (10*66);
        int rr  = rem / 66;
        int cc  = rem % 66;
        int gy = y0 - 1 + rr;
        int gx = cc - 1;
        float v = 0.f;
        if ((unsigned)gy < 64u && (unsigned)gx < 64u)
            v = in[(size_t)(b*CIN + ci)*HW_ + gy*64 + gx];
        slab[ci][rr][cc] = v;
    }
    __syncthreads();

    const int x  = tid & 63;
    const int ry = tid >> 6;

    float acc[16];
    #pragma unroll
    for (int co = 0; co < 16; co++) acc[co] = bb[co];

    for (int ci = 0; ci < CIN; ci++){
        float p[3][3];
        #pragma unroll
        for (int dy = 0; dy < 3; dy++)
            #pragma unroll
            for (int dx = 0; dx < 3; dx++)
                p[dy][dx] = slab[ci][ry + dy][x + dx];
        #pragma unroll
        for (int co = 0; co < 16; co++){
            const float* wp = w + (size_t)(co*CIN + ci)*9;
            float s = acc[co];
            #pragma unroll
            for (int dy = 0; dy < 3; dy++)
                #pragma unroll
                for (int dx = 0; dx < 3; dx++)
                    s = fmaf(wp[dy*3 + dx], p[dy][dx], s);
            acc[co] = s;
        }
    }
    #pragma unroll
    for (int co = 0; co < 16; co++){
        float v = acc[co];
        v = ACT ? fast_tanh(v) : fmaxf(v, 0.f);
        out[(size_t)(b*16 + co)*HW_ + (y0 + ry)*64 + x] = v;
    }
}

// ---------------------------------------------------------------------------
// 50-step coRNN ODE, row-segment ownership (4 x-consecutive px/thread).
// Stencil + state updates in packed f32x2 (v_pk_fma_f32 path); tanh scalar.
// LDS row stride 68 floats (16B-aligned rows). One packed 8B store/step.
// ---------------------------------------------------------------------------
__global__ __launch_bounds__(1024) void ode_kernel(
    const float* __restrict__ omega, const float* __restrict__ alpha,
    const float* __restrict__ hy0,   const float* __restrict__ wy,
    __half* __restrict__ yseq)
{
    __shared__ __align__(16) float buf[2][64*68];
    const int blk = blockIdx.x;            // b*16 + c
    const int c   = blk & 15;
    const int tid = threadIdx.x;
    const int y   = tid >> 4;              // 0..63
    const int xq  = (tid & 15) << 2;       // 0,4,...,60
    const size_t off = (size_t)blk * HW_;
    const int g0  = y*64 + xq;

    float4 om4 = *(const float4*)(omega + off + g0);
    float4 al4 = *(const float4*)(alpha + off + g0);
    float4 h4  = *(const float4*)(hy0   + off + g0);

    // packed preconditioned coefficients: om' = DT*om, al' = 1 - DT*al
    f32x2 om2[2] = { (f32x2){DT_*om4.x, DT_*om4.y}, (f32x2){DT_*om4.z, DT_*om4.w} };
    f32x2 al2[2] = { (f32x2){1.f - DT_*al4.x, 1.f - DT_*al4.y},
                     (f32x2){1.f - DT_*al4.z, 1.f - DT_*al4.w} };
    f32x2 hz2[2] = { (f32x2){0.f, 0.f}, (f32x2){0.f, 0.f} };
    float hv[4]  = { h4.x, h4.y, h4.z, h4.w };
    *(float4*)&buf[0][y*68 + xq] = h4;

    float wv[9];
    const float* wp = wy + (size_t)(c*C_ + c)*9;
    #pragma unroll
    for (int j = 0; j < 9; j++) wv[j] = wp[j];
    const bool five = (wv[0]==0.f) & (wv[2]==0.f) & (wv[6]==0.f) & (wv[8]==0.f);
    const f32x2 w1v = (f32x2){wv[1], wv[1]};
    const f32x2 w3v = (f32x2){wv[3], wv[3]};
    const f32x2 w4v = (f32x2){wv[4], wv[4]};
    const f32x2 w5v = (f32x2){wv[5], wv[5]};
    const f32x2 w7v = (f32x2){wv[7], wv[7]};
    const f32x2 dt2 = (f32x2){DT_, DT_};
    __syncthreads();

    const int ym = ((y + 63) & 63) * 68;
    const int yp = ((y + 1)  & 63) * 68;
    const int yo = y * 68;
    const int xm = (xq + 63) & 63;         // x-1 wrapped
    const int xp = (xq + 4)  & 63;         // x+4 wrapped
    const __half* ybase = yseq + off + g0;

    int cur = 0;
    for (int t = 0; t < T_; t++){
        const float* hp = buf[cur];
        float* hn = buf[cur ^ 1];
        float4 up4 = *(const float4*)&hp[ym + xq];
        float4 dn4 = *(const float4*)&hp[yp + xq];
        float lft = hp[yo + xm];
        float rgt = hp[yo + xp];

        float ny0, ny1, ny2, ny3;
        if (five){
            f32x2 u0 = (f32x2){up4.x, up4.y}, u1 = (f32x2){up4.z, up4.w};
            f32x2 d0 = (f32x2){dn4.x, dn4.y}, d1 = (f32x2){dn4.z, dn4.w};
            f32x2 c0 = (f32x2){hv[0], hv[1]}, c1 = (f32x2){hv[2], hv[3]};
            f32x2 l0 = (f32x2){lft,  hv[0]};
            f32x2 l1 = (f32x2){hv[1], hv[2]};   // == r0
            f32x2 r1 = (f32x2){hv[3], rgt};

            f32x2 s0 = w4v*c0 + w1v*u0 + w7v*d0 + w3v*l0 + w5v*l1;
            f32x2 s1 = w4v*c1 + w1v*u1 + w7v*d1 + w3v*l1 + w5v*r1;

            f32x2 sf0 = (f32x2){fast_tanh(s0.x), fast_tanh(s0.y)};
            f32x2 sf1 = (f32x2){fast_tanh(s1.x), fast_tanh(s1.y)};

            f32x2 nz0 = al2[0]*hz2[0] - om2[0]*c0 + dt2*sf0;
            f32x2 nz1 = al2[1]*hz2[1] - om2[1]*c1 + dt2*sf1;
            f32x2 nyv0 = dt2*nz0 + c0;
            f32x2 nyv1 = dt2*nz1 + c1;
            hz2[0] = nz0; hz2[1] = nz1;
            ny0 = nyv0.x; ny1 = nyv0.y; ny2 = nyv1.x; ny3 = nyv1.y;
        } else {
            float upv[4] = {up4.x, up4.y, up4.z, up4.w};
            float dnv[4] = {dn4.x, dn4.y, dn4.z, dn4.w};
            float ul = hp[ym + xm], ur = hp[ym + xp];
            float dl = hp[yp + xm], dr = hp[yp + xp];
            float hzl[4] = {hz2[0].x, hz2[0].y, hz2[1].x, hz2[1].y};
            float oml[4] = {om2[0].x, om2[0].y, om2[1].x, om2[1].y};
            float all[4] = {al2[0].x, al2[0].y, al2[1].x, al2[1].y};
            float nyv[4];
            #pragma unroll
            for (int i = 0; i < 4; i++){
                float l  = (i == 0) ? lft : hv[i-1];
                float r  = (i == 3) ? rgt : hv[i+1];
                float uL = (i == 0) ? ul  : upv[i-1];
                float uR = (i == 3) ? ur  : upv[i+1];
                float dL = (i == 0) ? dl  : dnv[i-1];
                float dR = (i == 3) ? dr  : dnv[i+1];
                float s = wv[0]*uL + wv[1]*upv[i] + wv[2]*uR
                        + wv[3]*l  + wv[4]*hv[i]  + wv[5]*r
                        + wv[6]*dL + wv[7]*dnv[i] + wv[8]*dR;
                float sf = fast_tanh(s);
                float nz = fmaf(all[i], hzl[i], fmaf(-oml[i], hv[i], DT_*sf));
                nyv[i] = fmaf(DT_, nz, hv[i]);
                hzl[i] = nz;
            }
            hz2[0] = (f32x2){hzl[0], hzl[1]};
            hz2[1] = (f32x2){hzl[2], hzl[3]};
            ny0 = nyv[0]; ny1 = nyv[1]; ny2 = nyv[2]; ny3 = nyv[3];
        }

        hv[0] = ny0; hv[1] = ny1; hv[2] = ny2; hv[3] = ny3;
        *(float4*)&hn[yo + xq] = make_float4(ny0, ny1, ny2, ny3);

        union { fp16x2 h2[2]; uint2 u; } pk;
        pk.h2[0] = __builtin_amdgcn_cvt_pkrtz(ny0, ny1);
        pk.h2[1] = __builtin_amdgcn_cvt_pkrtz(ny2, ny3);
        *(uint2*)(ybase + (size_t)t*BCHW_) = pk.u;

        __syncthreads();
        cur ^= 1;
    }
}

// ---------------------------------------------------------------------------
// MFMA DFT (unchanged). fp16 in/out.
// ---------------------------------------------------------------------------
__global__ __launch_bounds__(256) void dft_mfma_kernel(
    const __half* __restrict__ yseq, __half* __restrict__ f)
{
    __shared__ __align__(16) char Ys[8*256*16];
    __shared__ __align__(16) char Gs[8*64*16];
    const int tid = threadIdx.x;
    const int blk = blockIdx.x;
    const int bc  = blk >> 4;
    const int p0  = (blk & 15) << 8;
    const int b   = bc >> 4, c = bc & 15;

    for (int idx = tid; idx < 64*64; idx += 256){
        int r = idx >> 6, t = idx & 63;
        float v = 0.f;
        if (r < 52 && t < 50){
            int k  = r >> 1;
            int ph = (k * t) % 50;
            float ang = (float)ph * (6.2831853071795864f / 50.f);
            v = (r & 1) ? __sinf(ang) : __cosf(ang);
        }
        *(_Float16*)(Gs + ((t >> 3)*64 + r)*16 + (t & 7)*2) = (_Float16)v;
    }

    {
        const __half* src = yseq + (size_t)bc*HW_ + p0 + tid;
        #pragma unroll
        for (int t2 = 0; t2 < 25; t2++){
            unsigned int a = *(const unsigned short*)&src[(size_t)(2*t2)*BCHW_];
            unsigned int d = *(const unsigned short*)&src[(size_t)(2*t2+1)*BCHW_];
            int t8 = t2 >> 2, j = t2 & 3;
            *(unsigned int*)(Ys + (t8*256 + tid)*16 + j*4) = a | (d << 16);
        }
        #pragma unroll
        for (int t2 = 25; t2 < 32; t2++){
            int t8 = t2 >> 2, j = t2 & 3;
            *(unsigned int*)(Ys + (t8*256 + tid)*16 + j*4) = 0u;
        }
    }
    __syncthreads();

    const int lane = tid & 63;
    const int w    = tid >> 6;
    const int n    = lane & 15;
    const int quad = lane >> 4;
    const int mrow = 16*w + n;

    f16x8 a0 = *(const f16x8*)(Gs + ((quad    )*64 + mrow)*16);
    f16x8 a1 = *(const f16x8*)(Gs + ((quad + 4)*64 + mrow)*16);

    const int kb0   = 8*w + 2*quad;
    const bool valid = (kb0 < K_);

    for (int nt = 0; nt < 16; nt++){
        f16x8 b0 = *(const f16x8*)(Ys + ((quad    )*256 + nt*16 + n)*16);
        f16x8 b1 = *(const f16x8*)(Ys + ((quad + 4)*256 + nt*16 + n)*16);
        f32x4 acc = (f32x4){0.f, 0.f, 0.f, 0.f};
        acc = __builtin_amdgcn_mfma_f32_16x16x32_f16(a0, b0, acc, 0, 0, 0);
        acc = __builtin_amdgcn_mfma_f32_16x16x32_f16(a1, b1, acc, 0, 0, 0);
        if (valid){
            float m0 = sqrtf(fmaf(acc[0], acc[0], acc[1]*acc[1]));
            float m1 = sqrtf(fmaf(acc[2], acc[2], acc[3]*acc[3]));
            unsigned int u = ((unsigned int)(unsigned short)f2h_s(m1) << 16)
                           |  (unsigned int)(unsigned short)f2h_s(m0);
            const int row = b*HW_ + p0 + nt*16 + n;
            *(unsigned int*)((char*)(f + (size_t)row*F_ + c*K_) + kb0*2) = u;
        }
    }
}

// ---------------------------------------------------------------------------
// One merged prep kernel: wt1 [256][416], wt2/wt3 [256][256], all fp16.
// ---------------------------------------------------------------------------
__global__ __launch_bounds__(256) void prep_all_kernel(
    const float* __restrict__ w1, const float* __restrict__ w2,
    const float* __restrict__ w3,
    __half* __restrict__ wt1, __half* __restrict__ wt2, __half* __restrict__ wt3)
{
    const int blk = blockIdx.x;
    const int tid = threadIdx.x;
    if (blk < 256){
        const int n = blk;
        for (int k = tid; k < F_; k += 256)
            wt1[(size_t)n*F_ + k] = __float2half(w1[(size_t)k*HID_ + n]);
    } else if (blk < 512){
        const int n = blk - 256;
        for (int k = tid; k < HID_; k += 256)
            wt2[(size_t)n*HID_ + k] = __float2half(w2[(size_t)k*HID_ + n]);
    } else {
        const int n = blk - 512;
        for (int k = tid; k < HID_; k += 256)
            wt3[(size_t)n*HID_ + k] = __float2half(w3[(size_t)k*HID_ + n]);
    }
}

// ---------------------------------------------------------------------------
// FUSED MLP (unchanged from round 8).
// ---------------------------------------------------------------------------
__global__ __launch_bounds__(512, 2) void mlp_fused_kernel(
    const __half* __restrict__ A,     // fbuf [M][416]
    const __half* __restrict__ Wt1,   // [256][416]
    const __half* __restrict__ Wt2,   // [256][256]
    const __half* __restrict__ Wt3,   // [256][256]
    const float* __restrict__ b1, const float* __restrict__ b2,
    const float* __restrict__ b3,
    const float* __restrict__ w4, const float* __restrict__ b4,
    float* __restrict__ out)
{
    __shared__ __align__(16) short hbuf[256*264];   // 135,168 B
    __shared__ __align__(16) short Bs[4*2064];      //  16,512 B (4128 B/section)
    __shared__ __align__(16) short Bs4[512*8];      //   8,192 B (w4 fragments)

    const int tid  = threadIdx.x;
    const int lane = tid & 63;
    const int wave = tid >> 6;
    const int wm   = (wave & 3) * 64;
    const int wn   = (wave >> 2) * 128;
    const int n16  = lane & 15;
    const int quad = lane >> 4;
    const int m0   = blockIdx.x * 256;

    {
        const int ktq = tid >> 4, n = tid & 15;
        short vals[8];
        #pragma unroll
        for (int e = 0; e < 8; e++){
            const int k = ktq*8 + e;
            vals[e] = f2h_s((n < NC_) ? w4[(size_t)k*NC_ + n] : 0.f);
        }
        #pragma unroll
        for (int e = 0; e < 8; e++) Bs4[tid*8 + e] = vals[e];
    }

    const int id0 = tid, id1 = tid + 512;
    const int kc0 = id0 >> 8, nn0 = id0 & 255;
    const int kc1 = id1 >> 8, nn1 = id1 & 255;
    char* dst0 = (char*)Bs + kc0*4128 + nn0*16;
    char* dst1 = (char*)Bs + kc1*4128 + nn1*16;

    f32x4 acc[4][8];
    #pragma unroll
    for (int i = 0; i < 4; i++)
        #pragma unroll
        for (int j = 0; j < 8; j++)
            acc[i][j] = (f32x4){0.f,0.f,0.f,0.f};

    // ---------------- layer 1: A from global ----------------
    const __half* arow[4];
    #pragma unroll
    for (int i = 0; i < 4; i++)
        arow[i] = A + (size_t)(m0 + wm + i*16 + n16)*F_ + quad*8;

    f16x8 afn[4];
    #pragma unroll
    for (int i = 0; i < 4; i++) afn[i] = *(const f16x8*)(arow[i]);

    for (int k0 = 0; k0 < F_; k0 += 32){
        gld_lds16(Wt1 + (size_t)nn0*F_ + k0 + kc0*8, dst0);
        gld_lds16(Wt1 + (size_t)nn1*F_ + k0 + kc1*8, dst1);
        __syncthreads();
        f16x8 af[4];
        #pragma unroll
        for (int i = 0; i < 4; i++) af[i] = afn[i];
        if (k0 + 32 < F_){
            #pragma unroll
            for (int i = 0; i < 4; i++) afn[i] = *(const f16x8*)(arow[i] + k0 + 32);
        }
        f16x8 bf[8];
        #pragma unroll
        for (int j = 0; j < 8; j++)
            bf[j] = *(const f16x8*)((char*)Bs + quad*4128 + (wn + j*16 + n16)*16);
        #pragma unroll
        for (int i = 0; i < 4; i++)
            #pragma unroll
            for (int j = 0; j < 8; j++)
                acc[i][j] = __builtin_amdgcn_mfma_f32_16x16x32_f16(
                                af[i], bf[j], acc[i][j], 0, 0, 0);
        __syncthreads();
    }
    #pragma unroll
    for (int j = 0; j < 8; j++){
        const int col = wn + j*16 + n16;
        const float bv = b1[col];
        #pragma unroll
        for (int i = 0; i < 4; i++){
            const int r0 = wm + i*16 + quad*4;
            #pragma unroll
            for (int r = 0; r < 4; r++)
                hbuf[(r0 + r)*264 + col] = f2h_s(fmaxf(acc[i][j][r] + bv, 0.f));
        }
    }
    __syncthreads();

    // ---------------- layers 2,3: A from hbuf ----------------
    const __half* Wts[2] = {Wt2, Wt3};
    const float* bls[2] = {b2, b3};
    for (int L = 0; L < 2; L++){
        const __half* Wt = Wts[L];
        #pragma unroll
        for (int i = 0; i < 4; i++)
            #pragma unroll
            for (int j = 0; j < 8; j++)
                acc[i][j] = (f32x4){0.f,0.f,0.f,0.f};

        for (int k0 = 0; k0 < HID_; k0 += 32){
            gld_lds16(Wt + (size_t)nn0*HID_ + k0 + kc0*8, dst0);
            gld_lds16(Wt + (size_t)nn1*HID_ + k0 + kc1*8, dst1);
            f16x8 af[4];
            #pragma unroll
            for (int i = 0; i < 4; i++)
                af[i] = *(const f16x8*)&hbuf[(wm + i*16 + n16)*264 + k0 + quad*8];
            __syncthreads();
            f16x8 bf[8];
            #pragma unroll
            for (int j = 0; j < 8; j++)
                bf[j] = *(const f16x8*)((char*)Bs + quad*4128 + (wn + j*16 + n16)*16);
            #pragma unroll
            for (int i = 0; i < 4; i++)
                #pragma unroll
                for (int j = 0; j < 8; j++)
                    acc[i][j] = __builtin_amdgcn_mfma_f32_16x16x32_f16(
                                    af[i], bf[j], acc[i][j], 0, 0, 0);
            __syncthreads();
        }
        const float* bl = bls[L];
        #pragma unroll
        for (int j = 0; j < 8; j++){
            const int col = wn + j*16 + n16;
            const float bv = bl[col];
            #pragma unroll
            for (int i = 0; i < 4; i++){
                const int r0 = wm + i*16 + quad*4;
                #pragma unroll
                for (int r = 0; r < 4; r++)
                    hbuf[(r0 + r)*264 + col] = f2h_s(fmaxf(acc[i][j][r] + bv, 0.f));
            }
        }
        __syncthreads();
    }

    // ---------------- final layer 256 -> 7 as MFMA + NCHW transpose --------
    f32x4 facc[2] = {(f32x4){0.f,0.f,0.f,0.f}, (f32x4){0.f,0.f,0.f,0.f}};
    #pragma unroll
    for (int kt = 0; kt < 8; kt++){
        f16x8 bfr = *(const f16x8*)&Bs4[((kt*4 + quad)*16 + n16)*8];
        #pragma unroll
        for (int mt = 0; mt < 2; mt++){
            f16x8 af = *(const f16x8*)&hbuf[(wave*32 + mt*16 + n16)*264 + kt*32 + quad*8];
            facc[mt] = __builtin_amdgcn_mfma_f32_16x16x32_f16(af, bfr, facc[mt], 0, 0, 0);
        }
    }
    if (n16 < NC_){
        const float bv = b4[n16];
        #pragma unroll
        for (int mt = 0; mt < 2; mt++){
            #pragma unroll
            for (int r = 0; r < 4; r++){
                const int grow = m0 + wave*32 + mt*16 + quad*4 + r;
                const int bidx = grow >> 12, hw = grow & 4095;
                out[(size_t)(bidx*NC_ + n16)*HW_ + hw] = facc[mt][r] + bv;
            }
        }
    }
}

// ---------------------------------------------------------------------------
// Workspace (peak 159,383,552 B, proven):
//   yseq fp16 [50][256][4096] @ 0 (104,857,600)         ODE w, DFT r
//   fbuf fp16 [65536][416] @ 104,857,600 (54,525,952)   DFT w, MLP r
//     conv temps (10 x 4 MiB) aliased in fbuf region (dead before DFT)
//   wt1/2/3 fp16 @ 0 (yseq region, dead after DFT)
// ---------------------------------------------------------------------------
extern "C" void kernel_launch(void* const* d_in, const int* in_sizes, int n_in,
                              void* d_out, int out_size, void* d_ws, size_t ws_size,
                              hipStream_t stream)
{
    const float* x     = (const float*)d_in[0];
    const float* om_w1 = (const float*)d_in[1];  const float* om_b1 = (const float*)d_in[2];
    const float* om_w2 = (const float*)d_in[3];  const float* om_b2 = (const float*)d_in[4];
    const float* om_w3 = (const float*)d_in[5];  const float* om_b3 = (const float*)d_in[6];
    const float* al_w1 = (const float*)d_in[7];  const float* al_b1 = (const float*)d_in[8];
    const float* al_w2 = (const float*)d_in[9];  const float* al_b2 = (const float*)d_in[10];
    const float* al_w3 = (const float*)d_in[11]; const float* al_b3 = (const float*)d_in[12];
    const float* hy_w1 = (const float*)d_in[13]; const float* hy_b1 = (const float*)d_in[14];
    const float* hy_w2 = (const float*)d_in[15]; const float* hy_b2 = (const float*)d_in[16];
    const float* hy_w3 = (const float*)d_in[17]; const float* hy_b3 = (const float*)d_in[18];
    const float* hy_w4 = (const float*)d_in[19]; const float* hy_b4 = (const float*)d_in[20];
    const float* wy    = (const float*)d_in[21];
    const float* ro_w1 = (const float*)d_in[22]; const float* ro_b1 = (const float*)d_in[23];
    const float* ro_w2 = (const float*)d_in[24]; const float* ro_b2 = (const float*)d_in[25];
    const float* ro_w3 = (const float*)d_in[26]; const float* ro_b3 = (const float*)d_in[27];
    const float* ro_w4 = (const float*)d_in[28]; const float* ro_b4 = (const float*)d_in[29];
    float* out = (float*)d_out;

    char* wsb = (char*)d_ws;
    const size_t YSEQ_BYTES = (size_t)T_ * BCHW_ * 2;          // 104,857,600
    __half* yseq = (__half*)wsb;
    __half* fbuf = (__half*)(wsb + YSEQ_BYTES);

    const size_t MB4 = (size_t)BCHW_ * 4;                      // 4 MiB
    float* om_t1 = (float*)(wsb + YSEQ_BYTES + 0*MB4);
    float* al_t1 = (float*)(wsb + YSEQ_BYTES + 1*MB4);
    float* hy_t1 = (float*)(wsb + YSEQ_BYTES + 2*MB4);
    float* om_t2 = (float*)(wsb + YSEQ_BYTES + 3*MB4);
    float* al_t2 = (float*)(wsb + YSEQ_BYTES + 4*MB4);
    float* hy_t2 = (float*)(wsb + YSEQ_BYTES + 5*MB4);
    float* omega = (float*)(wsb + YSEQ_BYTES + 6*MB4);
    float* alpha = (float*)(wsb + YSEQ_BYTES + 7*MB4);
    float* hy_t3 = (float*)(wsb + YSEQ_BYTES + 8*MB4);
    float* hy0   = (float*)(wsb + YSEQ_BYTES + 9*MB4);

    __half* wt1 = (__half*)(wsb + 0);          // 212,992 B
    __half* wt2 = (__half*)(wsb + 212992);     // 131,072 B
    __half* wt3 = (__half*)(wsb + 344064);     // 131,072 B

    // encoders: 3 chains fused per layer, 8-row slices
    convf_kernel<1,0><<<dim3(8,B_,3), 512, 0, stream>>>(
        x, x, x, om_w1, al_w1, hy_w1, om_b1, al_b1, hy_b1, om_t1, al_t1, hy_t1);
    convf_kernel<16,0><<<dim3(8,B_,3), 512, 0, stream>>>(
        om_t1, al_t1, hy_t1, om_w2, al_w2, hy_w2, om_b2, al_b2, hy_b2, om_t2, al_t2, hy_t2);
    convf_kernel<16,0><<<dim3(8,B_,3), 512, 0, stream>>>(
        om_t2, al_t2, hy_t2, om_w3, al_w3, hy_w3, om_b3, al_b3, hy_b3, omega, alpha, hy_t3);
    convf_kernel<16,1><<<dim3(8,B_,1), 512, 0, stream>>>(
        hy_t3, hy_t3, hy_t3, hy_w4, hy_w4, hy_w4, hy_b4, hy_b4, hy_b4, hy0, hy0, hy0);
    // 50-step ODE (packed f32x2 math, fp16 yseq out)
    ode_kernel<<<256, 1024, 0, stream>>>(omega, alpha, hy0, wy, yseq);
    // MFMA DFT: rfft magnitude -> row-major fp16 features
    dft_mfma_kernel<<<4096, 256, 0, stream>>>(yseq, fbuf);
    // merged weight transposes (yseq dead; wt at workspace base)
    prep_all_kernel<<<768, 256, 0, stream>>>(ro_w1, ro_w2, ro_w3, wt1, wt2, wt3);
    // fused readout MLP (3 GEMMs + MFMA final layer + transpose)
    mlp_fused_kernel<<<256, 512, 0, stream>>>(
        fbuf, wt1, wt2, wt3, ro_b1, ro_b2, ro_b3, ro_w4, ro_b4, out);
}